// Round 1
// baseline (658.068 us; speedup 1.0000x reference)
//
#include <hip/hip_runtime.h>

#define N_NODES 100000
#define IN_CH 128
#define OUT_CH 64
#define HID 128
#define N_EDGES 1600000
#define TOT_E (N_EDGES + N_NODES)

// ---------------- setup: degree, dinv, CSR build ----------------

__global__ void k_init_deg(int* __restrict__ deg) {
    int i = blockIdx.x * blockDim.x + threadIdx.x;
    if (i < N_NODES) deg[i] = 1;  // self loop
}

__global__ void k_degree(const int* __restrict__ dst, int* __restrict__ deg) {
    int e = blockIdx.x * blockDim.x + threadIdx.x;
    if (e < N_EDGES) atomicAdd(&deg[dst[e]], 1);
}

__global__ void k_dinv(const int* __restrict__ deg, float* __restrict__ dinv) {
    int i = blockIdx.x * blockDim.x + threadIdx.x;
    if (i < N_NODES) dinv[i] = rsqrtf((float)deg[i]);
}

#define SCAN_T 1024
__global__ void k_scan_local(const int* __restrict__ deg, int* __restrict__ excl,
                             int* __restrict__ bsum, int n) {
    __shared__ int tmp[SCAN_T];
    int t = threadIdx.x;
    int i = blockIdx.x * SCAN_T + t;
    int v = (i < n) ? deg[i] : 0;
    tmp[t] = v;
    __syncthreads();
    for (int off = 1; off < SCAN_T; off <<= 1) {
        int u = (t >= off) ? tmp[t - off] : 0;
        __syncthreads();
        tmp[t] += u;
        __syncthreads();
    }
    if (i < n) excl[i] = tmp[t] - v;
    if (t == SCAN_T - 1) bsum[blockIdx.x] = tmp[t];
}

__global__ void k_scan_sums(const int* __restrict__ bsum, int* __restrict__ boff, int nb) {
    __shared__ int tmp[128];
    int t = threadIdx.x;
    int v = (t < nb) ? bsum[t] : 0;
    tmp[t] = v;
    __syncthreads();
    for (int off = 1; off < 128; off <<= 1) {
        int u = (t >= off) ? tmp[t - off] : 0;
        __syncthreads();
        tmp[t] += u;
        __syncthreads();
    }
    if (t < nb) boff[t] = tmp[t] - v;
}

__global__ void k_scan_add(const int* __restrict__ excl, const int* __restrict__ boff,
                           int* __restrict__ row_start, int* __restrict__ cursor, int n) {
    int i = blockIdx.x * blockDim.x + threadIdx.x;
    if (i < n) {
        int v = excl[i] + boff[i / SCAN_T];
        row_start[i] = v;
        cursor[i] = v;
    }
}

__global__ void k_fill_edges(const int* __restrict__ src, const int* __restrict__ dst,
                             const float* __restrict__ dinv, int* __restrict__ cursor,
                             int* __restrict__ csr_src, float* __restrict__ csr_w) {
    int e = blockIdx.x * blockDim.x + threadIdx.x;
    if (e < N_EDGES) {
        int d = dst[e];
        int s = src[e];
        int p = atomicAdd(&cursor[d], 1);
        csr_src[p] = s;
        csr_w[p] = dinv[s];
    }
}

__global__ void k_fill_self(const float* __restrict__ dinv, int* __restrict__ cursor,
                            int* __restrict__ csr_src, float* __restrict__ csr_w) {
    int i = blockIdx.x * blockDim.x + threadIdx.x;
    if (i < N_NODES) {
        int p = atomicAdd(&cursor[i], 1);
        csr_src[p] = i;
        csr_w[p] = dinv[i];
    }
}

// ---------------- aggregation: y[dst] = dinv[dst] * sum_e dinv[src]*x[src] ----------------
// one wave (64 lanes) per node; lane l holds channels 2l, 2l+1 (float2 -> 512B/row coalesced)

__global__ __launch_bounds__(256) void k_agg(const float* __restrict__ in, float* __restrict__ out,
                                             const int* __restrict__ csr_src,
                                             const float* __restrict__ csr_w,
                                             const int* __restrict__ row_start,
                                             const int* __restrict__ deg,
                                             const float* __restrict__ dinv) {
    int w = (blockIdx.x * 256 + threadIdx.x) >> 6;
    int lane = threadIdx.x & 63;
    if (w >= N_NODES) return;
    int beg = row_start[w];
    int cnt = deg[w];
    float2 acc = make_float2(0.f, 0.f);
    int j = 0;
    for (; j + 1 < cnt; j += 2) {
        int s0 = csr_src[beg + j];
        int s1 = csr_src[beg + j + 1];
        float w0 = csr_w[beg + j];
        float w1 = csr_w[beg + j + 1];
        float2 v0 = ((const float2*)(in + (size_t)s0 * 128))[lane];
        float2 v1 = ((const float2*)(in + (size_t)s1 * 128))[lane];
        acc.x += w0 * v0.x + w1 * v1.x;
        acc.y += w0 * v0.y + w1 * v1.y;
    }
    if (j < cnt) {
        int s0 = csr_src[beg + j];
        float w0 = csr_w[beg + j];
        float2 v0 = ((const float2*)(in + (size_t)s0 * 128))[lane];
        acc.x += w0 * v0.x;
        acc.y += w0 * v0.y;
    }
    float di = dinv[w];
    ((float2*)(out + (size_t)w * 128))[lane] = make_float2(di * acc.x, di * acc.y);
}

// ---------------- GEMM1: buf = relu_normalize(relu(buf @ W1 + b1)) in-place ----------------
// 32 rows x 128 cols per block (256 thr). W staged in LDS in two 64-row phases (48KB total LDS).
// thread t: cols [ (t&31)*4 , +4 ), rows { t>>5 + 8j, j=0..3 }  -> 16 accumulators.

__global__ __launch_bounds__(256) void k_gemm1(float* __restrict__ buf, const float* __restrict__ W,
                                               const float* __restrict__ b) {
    __shared__ float Wl[64 * 128];
    __shared__ float Al[32 * 128];
    int t = threadIdx.x;
    int r0 = blockIdx.x * 32;
    for (int i = t; i < 32 * 32; i += 256) {  // 32 rows * 32 float4
        int rr = i >> 5, cc = i & 31;
        int gr = r0 + rr;
        float4 v = make_float4(0.f, 0.f, 0.f, 0.f);
        if (gr < N_NODES) v = ((const float4*)(buf + (size_t)gr * 128))[cc];
        ((float4*)Al)[i] = v;
    }
    int cg = (t & 31) << 2;
    int rb = t >> 5;
    float4 acc[4];
    acc[0] = acc[1] = acc[2] = acc[3] = make_float4(0.f, 0.f, 0.f, 0.f);
    for (int p = 0; p < 2; p++) {
        __syncthreads();  // Al visible (p=0); Wl no longer read (p=1)
        for (int i = t; i < 64 * 32; i += 256) {  // 64 W-rows * 32 float4
            int kk = i >> 5, cc = i & 31;
            ((float4*)&Wl[kk * 128])[cc] = ((const float4*)&W[(size_t)(p * 64 + kk) * 128])[cc];
        }
        __syncthreads();
        #pragma unroll 4
        for (int k2 = 0; k2 < 64; k2++) {
            float4 wv = *(float4*)&Wl[k2 * 128 + cg];
            int kg = p * 64 + k2;
            #pragma unroll
            for (int j = 0; j < 4; j++) {
                float a = Al[(rb + 8 * j) * 128 + kg];
                acc[j].x = fmaf(a, wv.x, acc[j].x);
                acc[j].y = fmaf(a, wv.y, acc[j].y);
                acc[j].z = fmaf(a, wv.z, acc[j].z);
                acc[j].w = fmaf(a, wv.w, acc[j].w);
            }
        }
    }
    float4 bias = *(const float4*)&b[cg];
    #pragma unroll
    for (int j = 0; j < 4; j++) {
        int row = r0 + rb + 8 * j;
        float4 v = acc[j];
        v.x = fmaxf(v.x + bias.x, 0.f);
        v.y = fmaxf(v.y + bias.y, 0.f);
        v.z = fmaxf(v.z + bias.z, 0.f);
        v.w = fmaxf(v.w + bias.w, 0.f);
        float ssq = v.x * v.x + v.y * v.y + v.z * v.z + v.w * v.w;
        // reduce across the 32 threads (one half-wave) owning this row
        #pragma unroll
        for (int m = 1; m < 32; m <<= 1) ssq += __shfl_xor(ssq, m, 64);
        float s = 1.0f / fmaxf(sqrtf(ssq), 1e-12f);
        if (row < N_NODES) {
            float4 o = make_float4(v.x * s, v.y * s, v.z * s, v.w * s);
            *(float4*)(buf + (size_t)row * 128 + cg) = o;  // second relu is a no-op (all >= 0)
        }
    }
}

// ---------------- GEMM2: out = [ y2@Wmu+bmu | y2@Wls+bls ] split-written to d_out ----------------

__global__ __launch_bounds__(256) void k_gemm2(const float* __restrict__ bufin,
                                               const float* __restrict__ Wmu,
                                               const float* __restrict__ Wls,
                                               const float* __restrict__ bmu,
                                               const float* __restrict__ bls,
                                               float* __restrict__ out) {
    __shared__ float Wl[64 * 128];
    __shared__ float Al[32 * 128];
    int t = threadIdx.x;
    int r0 = blockIdx.x * 32;
    for (int i = t; i < 32 * 32; i += 256) {
        int rr = i >> 5, cc = i & 31;
        int gr = r0 + rr;
        float4 v = make_float4(0.f, 0.f, 0.f, 0.f);
        if (gr < N_NODES) v = ((const float4*)(bufin + (size_t)gr * 128))[cc];
        ((float4*)Al)[i] = v;
    }
    int cg = (t & 31) << 2;
    int rb = t >> 5;
    float4 acc[4];
    acc[0] = acc[1] = acc[2] = acc[3] = make_float4(0.f, 0.f, 0.f, 0.f);
    for (int p = 0; p < 2; p++) {
        __syncthreads();
        for (int i = t; i < 64 * 16; i += 256) {  // 64 W-rows * 16 float4 per half
            int kk = i >> 4, c4 = i & 15;
            ((float4*)&Wl[kk * 128])[c4]      = ((const float4*)&Wmu[(size_t)(p * 64 + kk) * 64])[c4];
            ((float4*)&Wl[kk * 128 + 64])[c4] = ((const float4*)&Wls[(size_t)(p * 64 + kk) * 64])[c4];
        }
        __syncthreads();
        #pragma unroll 4
        for (int k2 = 0; k2 < 64; k2++) {
            float4 wv = *(float4*)&Wl[k2 * 128 + cg];
            int kg = p * 64 + k2;
            #pragma unroll
            for (int j = 0; j < 4; j++) {
                float a = Al[(rb + 8 * j) * 128 + kg];
                acc[j].x = fmaf(a, wv.x, acc[j].x);
                acc[j].y = fmaf(a, wv.y, acc[j].y);
                acc[j].z = fmaf(a, wv.z, acc[j].z);
                acc[j].w = fmaf(a, wv.w, acc[j].w);
            }
        }
    }
    float4 bias = (cg < 64) ? ((const float4*)bmu)[cg >> 2] : ((const float4*)bls)[(cg - 64) >> 2];
    #pragma unroll
    for (int j = 0; j < 4; j++) {
        int row = r0 + rb + 8 * j;
        if (row < N_NODES) {
            float4 v = acc[j];
            v.x += bias.x; v.y += bias.y; v.z += bias.z; v.w += bias.w;
            float* dst = (cg < 64)
                ? out + (size_t)row * 64 + cg
                : out + (size_t)N_NODES * 64 + (size_t)row * 64 + (cg - 64);
            *(float4*)dst = v;
        }
    }
}

// ---------------- launch ----------------

extern "C" void kernel_launch(void* const* d_in, const int* in_sizes, int n_in,
                              void* d_out, int out_size, void* d_ws, size_t ws_size,
                              hipStream_t stream) {
    const float* x   = (const float*)d_in[0];
    const int*  eidx = (const int*)d_in[1];
    const float* W1  = (const float*)d_in[2];
    const float* b1  = (const float*)d_in[3];
    const float* Wmu = (const float*)d_in[4];
    const float* bmu = (const float*)d_in[5];
    const float* Wls = (const float*)d_in[6];
    const float* bls = (const float*)d_in[7];
    float* out = (float*)d_out;
    const int* e_src = eidx;
    const int* e_dst = eidx + N_EDGES;

    char* ws = (char*)d_ws;
    size_t off = 0;
    auto alloc = [&](size_t n) -> void* {
        void* p = ws + off;
        off += (n + 255) & ~(size_t)255;
        return p;
    };
    int*   deg       = (int*)alloc((size_t)N_NODES * sizeof(int));
    float* dinv      = (float*)alloc((size_t)N_NODES * sizeof(float));
    int*   excl      = (int*)alloc((size_t)N_NODES * sizeof(int));
    int*   bsum      = (int*)alloc(1024 * sizeof(int));
    int*   boff      = (int*)alloc(1024 * sizeof(int));
    int*   row_start = (int*)alloc((size_t)N_NODES * sizeof(int));
    int*   cursor    = (int*)alloc((size_t)N_NODES * sizeof(int));
    int*   csr_src   = (int*)alloc((size_t)TOT_E * sizeof(int));
    float* csr_w     = (float*)alloc((size_t)TOT_E * sizeof(float));
    float* buf1      = (float*)alloc((size_t)N_NODES * HID * sizeof(float));
    float* buf2      = (float*)alloc((size_t)N_NODES * HID * sizeof(float));

    const int NBLK_N = (N_NODES + 255) / 256;       // 391
    const int NBLK_E = (N_EDGES + 255) / 256;       // 6250
    const int NB_SCAN = (N_NODES + SCAN_T - 1) / SCAN_T;  // 98

    hipLaunchKernelGGL(k_init_deg, dim3(NBLK_N), dim3(256), 0, stream, deg);
    hipLaunchKernelGGL(k_degree, dim3(NBLK_E), dim3(256), 0, stream, e_dst, deg);
    hipLaunchKernelGGL(k_dinv, dim3(NBLK_N), dim3(256), 0, stream, deg, dinv);
    hipLaunchKernelGGL(k_scan_local, dim3(NB_SCAN), dim3(SCAN_T), 0, stream, deg, excl, bsum, N_NODES);
    hipLaunchKernelGGL(k_scan_sums, dim3(1), dim3(128), 0, stream, bsum, boff, NB_SCAN);
    hipLaunchKernelGGL(k_scan_add, dim3(NBLK_N), dim3(256), 0, stream, excl, boff, row_start, cursor, N_NODES);
    hipLaunchKernelGGL(k_fill_edges, dim3(NBLK_E), dim3(256), 0, stream, e_src, e_dst, dinv, cursor, csr_src, csr_w);
    hipLaunchKernelGGL(k_fill_self, dim3(NBLK_N), dim3(256), 0, stream, dinv, cursor, csr_src, csr_w);
    // layer 1: y1 = A @ x ; h = relu_norm(relu(y1 @ W1 + b1)) in-place in buf1
    hipLaunchKernelGGL(k_agg, dim3(N_NODES / 4), dim3(256), 0, stream, x, buf1, csr_src, csr_w, row_start, deg, dinv);
    hipLaunchKernelGGL(k_gemm1, dim3((N_NODES + 31) / 32), dim3(256), 0, stream, buf1, W1, b1);
    // layers 2+3 share one aggregation: y2 = A @ h
    hipLaunchKernelGGL(k_agg, dim3(N_NODES / 4), dim3(256), 0, stream, buf1, buf2, csr_src, csr_w, row_start, deg, dinv);
    hipLaunchKernelGGL(k_gemm2, dim3((N_NODES + 31) / 32), dim3(256), 0, stream, buf2, Wmu, Wls, bmu, bls, out);
}

// Round 2
// 544.820 us; speedup vs baseline: 1.2079x; 1.2079x over previous
//
#include <hip/hip_runtime.h>
#include <hip/hip_fp16.h>

#define N_NODES 100000
#define IN_CH 128
#define OUT_CH 64
#define HID 128
#define N_EDGES 1600000
#define TOT_E (N_EDGES + N_NODES)

// ---------------- setup: degree, dinv, CSR build ----------------

__global__ void k_init_deg(int* __restrict__ deg) {
    int i = blockIdx.x * blockDim.x + threadIdx.x;
    if (i < N_NODES) deg[i] = 1;  // self loop
}

__global__ void k_degree(const int* __restrict__ dst, int* __restrict__ deg) {
    int e = blockIdx.x * blockDim.x + threadIdx.x;
    if (e < N_EDGES) atomicAdd(&deg[dst[e]], 1);
}

__global__ void k_dinv(const int* __restrict__ deg, float* __restrict__ dinv) {
    int i = blockIdx.x * blockDim.x + threadIdx.x;
    if (i < N_NODES) dinv[i] = rsqrtf((float)deg[i]);
}

#define SCAN_T 1024
__global__ void k_scan_local(const int* __restrict__ deg, int* __restrict__ excl,
                             int* __restrict__ bsum, int n) {
    __shared__ int tmp[SCAN_T];
    int t = threadIdx.x;
    int i = blockIdx.x * SCAN_T + t;
    int v = (i < n) ? deg[i] : 0;
    tmp[t] = v;
    __syncthreads();
    for (int off = 1; off < SCAN_T; off <<= 1) {
        int u = (t >= off) ? tmp[t - off] : 0;
        __syncthreads();
        tmp[t] += u;
        __syncthreads();
    }
    if (i < n) excl[i] = tmp[t] - v;
    if (t == SCAN_T - 1) bsum[blockIdx.x] = tmp[t];
}

__global__ void k_scan_sums(const int* __restrict__ bsum, int* __restrict__ boff, int nb) {
    __shared__ int tmp[128];
    int t = threadIdx.x;
    int v = (t < nb) ? bsum[t] : 0;
    tmp[t] = v;
    __syncthreads();
    for (int off = 1; off < 128; off <<= 1) {
        int u = (t >= off) ? tmp[t - off] : 0;
        __syncthreads();
        tmp[t] += u;
        __syncthreads();
    }
    if (t < nb) boff[t] = tmp[t] - v;
}

__global__ void k_scan_add(const int* __restrict__ excl, const int* __restrict__ boff,
                           int* __restrict__ row_start, int* __restrict__ cursor, int n) {
    int i = blockIdx.x * blockDim.x + threadIdx.x;
    if (i < n) {
        int v = excl[i] + boff[i / SCAN_T];
        row_start[i] = v;
        cursor[i] = v;
    }
}

__global__ void k_fill_edges(const int* __restrict__ src, const int* __restrict__ dst,
                             const float* __restrict__ dinv, int* __restrict__ cursor,
                             int* __restrict__ csr_src, float* __restrict__ csr_w) {
    int e = blockIdx.x * blockDim.x + threadIdx.x;
    if (e < N_EDGES) {
        int d = dst[e];
        int s = src[e];
        int p = atomicAdd(&cursor[d], 1);
        csr_src[p] = s;
        csr_w[p] = dinv[s];
    }
}

__global__ void k_fill_self(const float* __restrict__ dinv, int* __restrict__ cursor,
                            int* __restrict__ csr_src, float* __restrict__ csr_w) {
    int i = blockIdx.x * blockDim.x + threadIdx.x;
    if (i < N_NODES) {
        int p = atomicAdd(&cursor[i], 1);
        csr_src[p] = i;
        csr_w[p] = dinv[i];
    }
}

// ---------------- fp32 -> fp16 cast for the gather-side feature matrix ----------------

__global__ __launch_bounds__(256) void k_cast_f2h(const float* __restrict__ in,
                                                  __half* __restrict__ out, int n4) {
    int i = blockIdx.x * blockDim.x + threadIdx.x;
    if (i < n4) {
        float4 v = ((const float4*)in)[i];
        ((__half2*)out)[2 * i]     = __floats2half2_rn(v.x, v.y);
        ((__half2*)out)[2 * i + 1] = __floats2half2_rn(v.z, v.w);
    }
}

// ---------------- aggregation: y[dst] = dinv[dst] * sum_e dinv[src]*x[src] ----------------
// fp16 rows (256B), f32 accumulate. one wave per node; lane l holds channels 2l,2l+1.

__global__ __launch_bounds__(256) void k_agg(const __half* __restrict__ in, __half* __restrict__ out,
                                             const int* __restrict__ csr_src,
                                             const float* __restrict__ csr_w,
                                             const int* __restrict__ row_start,
                                             const int* __restrict__ deg,
                                             const float* __restrict__ dinv) {
    int w = (blockIdx.x * 256 + threadIdx.x) >> 6;
    int lane = threadIdx.x & 63;
    if (w >= N_NODES) return;
    int beg = row_start[w];
    int cnt = deg[w];
    float2 acc = make_float2(0.f, 0.f);
    int j = 0;
    for (; j + 3 < cnt; j += 4) {
        int s0 = csr_src[beg + j];
        int s1 = csr_src[beg + j + 1];
        int s2 = csr_src[beg + j + 2];
        int s3 = csr_src[beg + j + 3];
        float w0 = csr_w[beg + j];
        float w1 = csr_w[beg + j + 1];
        float w2 = csr_w[beg + j + 2];
        float w3 = csr_w[beg + j + 3];
        float2 v0 = __half22float2(((const __half2*)(in + (size_t)s0 * 128))[lane]);
        float2 v1 = __half22float2(((const __half2*)(in + (size_t)s1 * 128))[lane]);
        float2 v2 = __half22float2(((const __half2*)(in + (size_t)s2 * 128))[lane]);
        float2 v3 = __half22float2(((const __half2*)(in + (size_t)s3 * 128))[lane]);
        acc.x += w0 * v0.x + w1 * v1.x + w2 * v2.x + w3 * v3.x;
        acc.y += w0 * v0.y + w1 * v1.y + w2 * v2.y + w3 * v3.y;
    }
    for (; j < cnt; j++) {
        int s0 = csr_src[beg + j];
        float w0 = csr_w[beg + j];
        float2 v0 = __half22float2(((const __half2*)(in + (size_t)s0 * 128))[lane]);
        acc.x += w0 * v0.x;
        acc.y += w0 * v0.y;
    }
    float di = dinv[w];
    ((__half2*)(out + (size_t)w * 128))[lane] = __floats2half2_rn(di * acc.x, di * acc.y);
}

// ---------------- GEMM1: buf = relu_normalize(relu(buf @ W1 + b1)) in-place (fp16 io) ----------------
// 32 rows x 128 cols per block (256 thr). W staged in LDS in two 64-row phases (48KB total LDS).
// thread t: cols [ (t&31)*4 , +4 ), rows { t>>5 + 8j, j=0..3 }  -> 16 accumulators.

__global__ __launch_bounds__(256) void k_gemm1(__half* __restrict__ buf, const float* __restrict__ W,
                                               const float* __restrict__ b) {
    __shared__ float Wl[64 * 128];
    __shared__ float Al[32 * 128];
    int t = threadIdx.x;
    int r0 = blockIdx.x * 32;
    for (int i = t; i < 32 * 16; i += 256) {  // 32 rows * 16 chunks of 8 halves (16B)
        int rr = i >> 4, cc = i & 15;
        int gr = r0 + rr;
        float2 f0 = make_float2(0.f, 0.f), f1 = f0, f2 = f0, f3 = f0;
        if (gr < N_NODES) {
            const __half2* p = (const __half2*)(buf + (size_t)gr * 128) + cc * 4;
            f0 = __half22float2(p[0]);
            f1 = __half22float2(p[1]);
            f2 = __half22float2(p[2]);
            f3 = __half22float2(p[3]);
        }
        float* dp = &Al[rr * 128 + cc * 8];
        *(float4*)(dp)     = make_float4(f0.x, f0.y, f1.x, f1.y);
        *(float4*)(dp + 4) = make_float4(f2.x, f2.y, f3.x, f3.y);
    }
    int cg = (t & 31) << 2;
    int rb = t >> 5;
    float4 acc[4];
    acc[0] = acc[1] = acc[2] = acc[3] = make_float4(0.f, 0.f, 0.f, 0.f);
    for (int p = 0; p < 2; p++) {
        __syncthreads();  // Al visible (p=0); Wl no longer read (p=1)
        for (int i = t; i < 64 * 32; i += 256) {  // 64 W-rows * 32 float4
            int kk = i >> 5, cc = i & 31;
            ((float4*)&Wl[kk * 128])[cc] = ((const float4*)&W[(size_t)(p * 64 + kk) * 128])[cc];
        }
        __syncthreads();
        #pragma unroll 4
        for (int k2 = 0; k2 < 64; k2++) {
            float4 wv = *(float4*)&Wl[k2 * 128 + cg];
            int kg = p * 64 + k2;
            #pragma unroll
            for (int j = 0; j < 4; j++) {
                float a = Al[(rb + 8 * j) * 128 + kg];
                acc[j].x = fmaf(a, wv.x, acc[j].x);
                acc[j].y = fmaf(a, wv.y, acc[j].y);
                acc[j].z = fmaf(a, wv.z, acc[j].z);
                acc[j].w = fmaf(a, wv.w, acc[j].w);
            }
        }
    }
    float4 bias = *(const float4*)&b[cg];
    #pragma unroll
    for (int j = 0; j < 4; j++) {
        int row = r0 + rb + 8 * j;
        float4 v = acc[j];
        v.x = fmaxf(v.x + bias.x, 0.f);
        v.y = fmaxf(v.y + bias.y, 0.f);
        v.z = fmaxf(v.z + bias.z, 0.f);
        v.w = fmaxf(v.w + bias.w, 0.f);
        float ssq = v.x * v.x + v.y * v.y + v.z * v.z + v.w * v.w;
        // reduce across the 32 threads (one half-wave) owning this row
        #pragma unroll
        for (int m = 1; m < 32; m <<= 1) ssq += __shfl_xor(ssq, m, 64);
        float s = 1.0f / fmaxf(sqrtf(ssq), 1e-12f);
        if (row < N_NODES) {
            __half2* dp = (__half2*)(buf + (size_t)row * 128 + cg);
            dp[0] = __floats2half2_rn(v.x * s, v.y * s);  // second relu is a no-op (all >= 0)
            dp[1] = __floats2half2_rn(v.z * s, v.w * s);
        }
    }
}

// ---------------- GEMM2: out = [ y2@Wmu+bmu | y2@Wls+bls ] split-written to d_out ----------------

__global__ __launch_bounds__(256) void k_gemm2(const __half* __restrict__ bufin,
                                               const float* __restrict__ Wmu,
                                               const float* __restrict__ Wls,
                                               const float* __restrict__ bmu,
                                               const float* __restrict__ bls,
                                               float* __restrict__ out) {
    __shared__ float Wl[64 * 128];
    __shared__ float Al[32 * 128];
    int t = threadIdx.x;
    int r0 = blockIdx.x * 32;
    for (int i = t; i < 32 * 16; i += 256) {
        int rr = i >> 4, cc = i & 15;
        int gr = r0 + rr;
        float2 f0 = make_float2(0.f, 0.f), f1 = f0, f2 = f0, f3 = f0;
        if (gr < N_NODES) {
            const __half2* p = (const __half2*)(bufin + (size_t)gr * 128) + cc * 4;
            f0 = __half22float2(p[0]);
            f1 = __half22float2(p[1]);
            f2 = __half22float2(p[2]);
            f3 = __half22float2(p[3]);
        }
        float* dp = &Al[rr * 128 + cc * 8];
        *(float4*)(dp)     = make_float4(f0.x, f0.y, f1.x, f1.y);
        *(float4*)(dp + 4) = make_float4(f2.x, f2.y, f3.x, f3.y);
    }
    int cg = (t & 31) << 2;
    int rb = t >> 5;
    float4 acc[4];
    acc[0] = acc[1] = acc[2] = acc[3] = make_float4(0.f, 0.f, 0.f, 0.f);
    for (int p = 0; p < 2; p++) {
        __syncthreads();
        for (int i = t; i < 64 * 16; i += 256) {  // 64 W-rows * 16 float4 per half
            int kk = i >> 4, c4 = i & 15;
            ((float4*)&Wl[kk * 128])[c4]      = ((const float4*)&Wmu[(size_t)(p * 64 + kk) * 64])[c4];
            ((float4*)&Wl[kk * 128 + 64])[c4] = ((const float4*)&Wls[(size_t)(p * 64 + kk) * 64])[c4];
        }
        __syncthreads();
        #pragma unroll 4
        for (int k2 = 0; k2 < 64; k2++) {
            float4 wv = *(float4*)&Wl[k2 * 128 + cg];
            int kg = p * 64 + k2;
            #pragma unroll
            for (int j = 0; j < 4; j++) {
                float a = Al[(rb + 8 * j) * 128 + kg];
                acc[j].x = fmaf(a, wv.x, acc[j].x);
                acc[j].y = fmaf(a, wv.y, acc[j].y);
                acc[j].z = fmaf(a, wv.z, acc[j].z);
                acc[j].w = fmaf(a, wv.w, acc[j].w);
            }
        }
    }
    float4 bias = (cg < 64) ? ((const float4*)bmu)[cg >> 2] : ((const float4*)bls)[(cg - 64) >> 2];
    #pragma unroll
    for (int j = 0; j < 4; j++) {
        int row = r0 + rb + 8 * j;
        if (row < N_NODES) {
            float4 v = acc[j];
            v.x += bias.x; v.y += bias.y; v.z += bias.z; v.w += bias.w;
            float* dst = (cg < 64)
                ? out + (size_t)row * 64 + cg
                : out + (size_t)N_NODES * 64 + (size_t)row * 64 + (cg - 64);
            *(float4*)dst = v;
        }
    }
}

// ---------------- launch ----------------

extern "C" void kernel_launch(void* const* d_in, const int* in_sizes, int n_in,
                              void* d_out, int out_size, void* d_ws, size_t ws_size,
                              hipStream_t stream) {
    const float* x   = (const float*)d_in[0];
    const int*  eidx = (const int*)d_in[1];
    const float* W1  = (const float*)d_in[2];
    const float* b1  = (const float*)d_in[3];
    const float* Wmu = (const float*)d_in[4];
    const float* bmu = (const float*)d_in[5];
    const float* Wls = (const float*)d_in[6];
    const float* bls = (const float*)d_in[7];
    float* out = (float*)d_out;
    const int* e_src = eidx;
    const int* e_dst = eidx + N_EDGES;

    char* ws = (char*)d_ws;
    size_t off = 0;
    auto alloc = [&](size_t n) -> void* {
        void* p = ws + off;
        off += (n + 255) & ~(size_t)255;
        return p;
    };
    int*    deg       = (int*)alloc((size_t)N_NODES * sizeof(int));
    float*  dinv      = (float*)alloc((size_t)N_NODES * sizeof(float));
    int*    excl      = (int*)alloc((size_t)N_NODES * sizeof(int));
    int*    bsum      = (int*)alloc(1024 * sizeof(int));
    int*    boff      = (int*)alloc(1024 * sizeof(int));
    int*    row_start = (int*)alloc((size_t)N_NODES * sizeof(int));
    int*    cursor    = (int*)alloc((size_t)N_NODES * sizeof(int));
    int*    csr_src   = (int*)alloc((size_t)TOT_E * sizeof(int));
    float*  csr_w     = (float*)alloc((size_t)TOT_E * sizeof(float));
    __half* xh        = (__half*)alloc((size_t)N_NODES * IN_CH * sizeof(__half));
    __half* bufA      = (__half*)alloc((size_t)N_NODES * HID * sizeof(__half));  // y1, then h
    __half* bufB      = (__half*)alloc((size_t)N_NODES * HID * sizeof(__half));  // y2

    const int NBLK_N = (N_NODES + 255) / 256;       // 391
    const int NBLK_E = (N_EDGES + 255) / 256;       // 6250
    const int NB_SCAN = (N_NODES + SCAN_T - 1) / SCAN_T;  // 98
    const int NCAST = (N_NODES * IN_CH / 4 + 255) / 256;

    hipLaunchKernelGGL(k_init_deg, dim3(NBLK_N), dim3(256), 0, stream, deg);
    hipLaunchKernelGGL(k_degree, dim3(NBLK_E), dim3(256), 0, stream, e_dst, deg);
    hipLaunchKernelGGL(k_cast_f2h, dim3(NCAST), dim3(256), 0, stream, x, xh, N_NODES * IN_CH / 4);
    hipLaunchKernelGGL(k_dinv, dim3(NBLK_N), dim3(256), 0, stream, deg, dinv);
    hipLaunchKernelGGL(k_scan_local, dim3(NB_SCAN), dim3(SCAN_T), 0, stream, deg, excl, bsum, N_NODES);
    hipLaunchKernelGGL(k_scan_sums, dim3(1), dim3(128), 0, stream, bsum, boff, NB_SCAN);
    hipLaunchKernelGGL(k_scan_add, dim3(NBLK_N), dim3(256), 0, stream, excl, boff, row_start, cursor, N_NODES);
    hipLaunchKernelGGL(k_fill_edges, dim3(NBLK_E), dim3(256), 0, stream, e_src, e_dst, dinv, cursor, csr_src, csr_w);
    hipLaunchKernelGGL(k_fill_self, dim3(NBLK_N), dim3(256), 0, stream, dinv, cursor, csr_src, csr_w);
    // layer 1: y1 = A @ x ; h = relu_norm(relu(y1 @ W1 + b1)) in-place in bufA
    hipLaunchKernelGGL(k_agg, dim3(N_NODES / 4), dim3(256), 0, stream, xh, bufA, csr_src, csr_w, row_start, deg, dinv);
    hipLaunchKernelGGL(k_gemm1, dim3((N_NODES + 31) / 32), dim3(256), 0, stream, bufA, W1, b1);
    // layers 2+3 share one aggregation: y2 = A @ h
    hipLaunchKernelGGL(k_agg, dim3(N_NODES / 4), dim3(256), 0, stream, bufA, bufB, csr_src, csr_w, row_start, deg, dinv);
    hipLaunchKernelGGL(k_gemm2, dim3((N_NODES + 31) / 32), dim3(256), 0, stream, bufB, Wmu, Wls, bmu, bls, out);
}

// Round 3
// 543.824 us; speedup vs baseline: 1.2101x; 1.0018x over previous
//
#include <hip/hip_runtime.h>
#include <hip/hip_fp16.h>

#define N_NODES 100000
#define IN_CH 128
#define OUT_CH 64
#define HID 128
#define N_EDGES 1600000

// ---------------- setup: degree (edges only), dinv = rsqrt(1+deg), CSR build ----------------

__global__ void k_init_deg(int* __restrict__ deg) {
    int i = blockIdx.x * blockDim.x + threadIdx.x;
    if (i < N_NODES) deg[i] = 0;
}

__global__ void k_degree(const int* __restrict__ dst, int* __restrict__ deg) {
    int e = blockIdx.x * blockDim.x + threadIdx.x;
    if (e < N_EDGES) atomicAdd(&deg[dst[e]], 1);
}

__global__ void k_dinv(const int* __restrict__ deg, float* __restrict__ dinv) {
    int i = blockIdx.x * blockDim.x + threadIdx.x;
    if (i < N_NODES) dinv[i] = rsqrtf((float)(deg[i] + 1));  // +1 self loop
}

#define SCAN_T 1024
__global__ void k_scan_local(const int* __restrict__ deg, int* __restrict__ excl,
                             int* __restrict__ bsum, int n) {
    __shared__ int tmp[SCAN_T];
    int t = threadIdx.x;
    int i = blockIdx.x * SCAN_T + t;
    int v = (i < n) ? deg[i] : 0;
    tmp[t] = v;
    __syncthreads();
    for (int off = 1; off < SCAN_T; off <<= 1) {
        int u = (t >= off) ? tmp[t - off] : 0;
        __syncthreads();
        tmp[t] += u;
        __syncthreads();
    }
    if (i < n) excl[i] = tmp[t] - v;
    if (t == SCAN_T - 1) bsum[blockIdx.x] = tmp[t];
}

__global__ void k_scan_sums(const int* __restrict__ bsum, int* __restrict__ boff, int nb) {
    __shared__ int tmp[128];
    int t = threadIdx.x;
    int v = (t < nb) ? bsum[t] : 0;
    tmp[t] = v;
    __syncthreads();
    for (int off = 1; off < 128; off <<= 1) {
        int u = (t >= off) ? tmp[t - off] : 0;
        __syncthreads();
        tmp[t] += u;
        __syncthreads();
    }
    if (t < nb) boff[t] = tmp[t] - v;
}

__global__ void k_scan_add(const int* __restrict__ excl, const int* __restrict__ boff,
                           int* __restrict__ row_start, int* __restrict__ cursor, int n) {
    int i = blockIdx.x * blockDim.x + threadIdx.x;
    if (i < n) {
        int v = excl[i] + boff[i / SCAN_T];
        row_start[i] = v;
        cursor[i] = v;
    }
}

__global__ void k_fill_edges(const int* __restrict__ src, const int* __restrict__ dst,
                             int* __restrict__ cursor, int* __restrict__ csr_src) {
    int e = blockIdx.x * blockDim.x + threadIdx.x;
    if (e < N_EDGES) {
        int d = dst[e];
        int p = atomicAdd(&cursor[d], 1);
        csr_src[p] = src[e];
    }
}

// ---------------- fp32 -> fp16 cast for the gather-side feature matrix ----------------

__global__ __launch_bounds__(256) void k_cast_f2h(const float* __restrict__ in,
                                                  __half* __restrict__ out, int n4) {
    int i = blockIdx.x * blockDim.x + threadIdx.x;
    if (i < n4) {
        float4 v = ((const float4*)in)[i];
        ((__half2*)out)[2 * i]     = __floats2half2_rn(v.x, v.y);
        ((__half2*)out)[2 * i + 1] = __floats2half2_rn(v.z, v.w);
    }
}

// ---------------- aggregation: y[w] = dinv[w] * ( dinv[w]*x[w] + sum_e dinv[s]*x[s] ) --------
// fp16 rows (256B), f32 accumulate. one wave per node; lane l holds channels 2l,2l+1.
// weight dinv[s] read directly (400KB, L2-resident broadcast load).

__global__ __launch_bounds__(256) void k_agg(const __half* __restrict__ in, __half* __restrict__ out,
                                             const int* __restrict__ csr_src,
                                             const int* __restrict__ row_start,
                                             const int* __restrict__ deg,
                                             const float* __restrict__ dinv) {
    int w = (blockIdx.x * 256 + threadIdx.x) >> 6;
    int lane = threadIdx.x & 63;
    if (w >= N_NODES) return;
    int beg = row_start[w];
    int cnt = deg[w];
    float di = dinv[w];
    // self-loop term: coef = dinv[w]^2 (outer di applied at the end)
    float2 xv = __half22float2(((const __half2*)(in + (size_t)w * 128))[lane]);
    float2 acc = make_float2(di * xv.x, di * xv.y);
    int j = 0;
    for (; j + 7 < cnt; j += 8) {
        int s0 = csr_src[beg + j];
        int s1 = csr_src[beg + j + 1];
        int s2 = csr_src[beg + j + 2];
        int s3 = csr_src[beg + j + 3];
        int s4 = csr_src[beg + j + 4];
        int s5 = csr_src[beg + j + 5];
        int s6 = csr_src[beg + j + 6];
        int s7 = csr_src[beg + j + 7];
        float w0 = dinv[s0], w1 = dinv[s1], w2 = dinv[s2], w3 = dinv[s3];
        float w4 = dinv[s4], w5 = dinv[s5], w6 = dinv[s6], w7 = dinv[s7];
        float2 v0 = __half22float2(((const __half2*)(in + (size_t)s0 * 128))[lane]);
        float2 v1 = __half22float2(((const __half2*)(in + (size_t)s1 * 128))[lane]);
        float2 v2 = __half22float2(((const __half2*)(in + (size_t)s2 * 128))[lane]);
        float2 v3 = __half22float2(((const __half2*)(in + (size_t)s3 * 128))[lane]);
        float2 v4 = __half22float2(((const __half2*)(in + (size_t)s4 * 128))[lane]);
        float2 v5 = __half22float2(((const __half2*)(in + (size_t)s5 * 128))[lane]);
        float2 v6 = __half22float2(((const __half2*)(in + (size_t)s6 * 128))[lane]);
        float2 v7 = __half22float2(((const __half2*)(in + (size_t)s7 * 128))[lane]);
        acc.x += w0 * v0.x + w1 * v1.x + w2 * v2.x + w3 * v3.x
               + w4 * v4.x + w5 * v5.x + w6 * v6.x + w7 * v7.x;
        acc.y += w0 * v0.y + w1 * v1.y + w2 * v2.y + w3 * v3.y
               + w4 * v4.y + w5 * v5.y + w6 * v6.y + w7 * v7.y;
    }
    for (; j + 3 < cnt; j += 4) {
        int s0 = csr_src[beg + j];
        int s1 = csr_src[beg + j + 1];
        int s2 = csr_src[beg + j + 2];
        int s3 = csr_src[beg + j + 3];
        float w0 = dinv[s0], w1 = dinv[s1], w2 = dinv[s2], w3 = dinv[s3];
        float2 v0 = __half22float2(((const __half2*)(in + (size_t)s0 * 128))[lane]);
        float2 v1 = __half22float2(((const __half2*)(in + (size_t)s1 * 128))[lane]);
        float2 v2 = __half22float2(((const __half2*)(in + (size_t)s2 * 128))[lane]);
        float2 v3 = __half22float2(((const __half2*)(in + (size_t)s3 * 128))[lane]);
        acc.x += w0 * v0.x + w1 * v1.x + w2 * v2.x + w3 * v3.x;
        acc.y += w0 * v0.y + w1 * v1.y + w2 * v2.y + w3 * v3.y;
    }
    for (; j < cnt; j++) {
        int s0 = csr_src[beg + j];
        float w0 = dinv[s0];
        float2 v0 = __half22float2(((const __half2*)(in + (size_t)s0 * 128))[lane]);
        acc.x += w0 * v0.x;
        acc.y += w0 * v0.y;
    }
    ((__half2*)(out + (size_t)w * 128))[lane] = __floats2half2_rn(di * acc.x, di * acc.y);
}

// ---------------- GEMM1: buf = relu_normalize(relu(buf @ W1 + b1)) in-place (fp16 io) ----------------
// 32 rows x 128 cols per block (256 thr). W staged in LDS in two 64-row phases (48KB total LDS).
// thread t: cols [ (t&31)*4 , +4 ), rows { t>>5 + 8j, j=0..3 }  -> 16 accumulators.

__global__ __launch_bounds__(256) void k_gemm1(__half* __restrict__ buf, const float* __restrict__ W,
                                               const float* __restrict__ b) {
    __shared__ float Wl[64 * 128];
    __shared__ float Al[32 * 128];
    int t = threadIdx.x;
    int r0 = blockIdx.x * 32;
    for (int i = t; i < 32 * 16; i += 256) {  // 32 rows * 16 chunks of 8 halves (16B)
        int rr = i >> 4, cc = i & 15;
        int gr = r0 + rr;
        float2 f0 = make_float2(0.f, 0.f), f1 = f0, f2 = f0, f3 = f0;
        if (gr < N_NODES) {
            const __half2* p = (const __half2*)(buf + (size_t)gr * 128) + cc * 4;
            f0 = __half22float2(p[0]);
            f1 = __half22float2(p[1]);
            f2 = __half22float2(p[2]);
            f3 = __half22float2(p[3]);
        }
        float* dp = &Al[rr * 128 + cc * 8];
        *(float4*)(dp)     = make_float4(f0.x, f0.y, f1.x, f1.y);
        *(float4*)(dp + 4) = make_float4(f2.x, f2.y, f3.x, f3.y);
    }
    int cg = (t & 31) << 2;
    int rb = t >> 5;
    float4 acc[4];
    acc[0] = acc[1] = acc[2] = acc[3] = make_float4(0.f, 0.f, 0.f, 0.f);
    for (int p = 0; p < 2; p++) {
        __syncthreads();  // Al visible (p=0); Wl no longer read (p=1)
        for (int i = t; i < 64 * 32; i += 256) {  // 64 W-rows * 32 float4
            int kk = i >> 5, cc = i & 31;
            ((float4*)&Wl[kk * 128])[cc] = ((const float4*)&W[(size_t)(p * 64 + kk) * 128])[cc];
        }
        __syncthreads();
        #pragma unroll 4
        for (int k2 = 0; k2 < 64; k2++) {
            float4 wv = *(float4*)&Wl[k2 * 128 + cg];
            int kg = p * 64 + k2;
            #pragma unroll
            for (int j = 0; j < 4; j++) {
                float a = Al[(rb + 8 * j) * 128 + kg];
                acc[j].x = fmaf(a, wv.x, acc[j].x);
                acc[j].y = fmaf(a, wv.y, acc[j].y);
                acc[j].z = fmaf(a, wv.z, acc[j].z);
                acc[j].w = fmaf(a, wv.w, acc[j].w);
            }
        }
    }
    float4 bias = *(const float4*)&b[cg];
    #pragma unroll
    for (int j = 0; j < 4; j++) {
        int row = r0 + rb + 8 * j;
        float4 v = acc[j];
        v.x = fmaxf(v.x + bias.x, 0.f);
        v.y = fmaxf(v.y + bias.y, 0.f);
        v.z = fmaxf(v.z + bias.z, 0.f);
        v.w = fmaxf(v.w + bias.w, 0.f);
        float ssq = v.x * v.x + v.y * v.y + v.z * v.z + v.w * v.w;
        // reduce across the 32 threads (one half-wave) owning this row
        #pragma unroll
        for (int m = 1; m < 32; m <<= 1) ssq += __shfl_xor(ssq, m, 64);
        float s = 1.0f / fmaxf(sqrtf(ssq), 1e-12f);
        if (row < N_NODES) {
            __half2* dp = (__half2*)(buf + (size_t)row * 128 + cg);
            dp[0] = __floats2half2_rn(v.x * s, v.y * s);  // second relu is a no-op (all >= 0)
            dp[1] = __floats2half2_rn(v.z * s, v.w * s);
        }
    }
}

// ---------------- GEMM2: out = [ y2@Wmu+bmu | y2@Wls+bls ] split-written to d_out ----------------

__global__ __launch_bounds__(256) void k_gemm2(const __half* __restrict__ bufin,
                                               const float* __restrict__ Wmu,
                                               const float* __restrict__ Wls,
                                               const float* __restrict__ bmu,
                                               const float* __restrict__ bls,
                                               float* __restrict__ out) {
    __shared__ float Wl[64 * 128];
    __shared__ float Al[32 * 128];
    int t = threadIdx.x;
    int r0 = blockIdx.x * 32;
    for (int i = t; i < 32 * 16; i += 256) {
        int rr = i >> 4, cc = i & 15;
        int gr = r0 + rr;
        float2 f0 = make_float2(0.f, 0.f), f1 = f0, f2 = f0, f3 = f0;
        if (gr < N_NODES) {
            const __half2* p = (const __half2*)(bufin + (size_t)gr * 128) + cc * 4;
            f0 = __half22float2(p[0]);
            f1 = __half22float2(p[1]);
            f2 = __half22float2(p[2]);
            f3 = __half22float2(p[3]);
        }
        float* dp = &Al[rr * 128 + cc * 8];
        *(float4*)(dp)     = make_float4(f0.x, f0.y, f1.x, f1.y);
        *(float4*)(dp + 4) = make_float4(f2.x, f2.y, f3.x, f3.y);
    }
    int cg = (t & 31) << 2;
    int rb = t >> 5;
    float4 acc[4];
    acc[0] = acc[1] = acc[2] = acc[3] = make_float4(0.f, 0.f, 0.f, 0.f);
    for (int p = 0; p < 2; p++) {
        __syncthreads();
        for (int i = t; i < 64 * 16; i += 256) {  // 64 W-rows * 16 float4 per half
            int kk = i >> 4, c4 = i & 15;
            ((float4*)&Wl[kk * 128])[c4]      = ((const float4*)&Wmu[(size_t)(p * 64 + kk) * 64])[c4];
            ((float4*)&Wl[kk * 128 + 64])[c4] = ((const float4*)&Wls[(size_t)(p * 64 + kk) * 64])[c4];
        }
        __syncthreads();
        #pragma unroll 4
        for (int k2 = 0; k2 < 64; k2++) {
            float4 wv = *(float4*)&Wl[k2 * 128 + cg];
            int kg = p * 64 + k2;
            #pragma unroll
            for (int j = 0; j < 4; j++) {
                float a = Al[(rb + 8 * j) * 128 + kg];
                acc[j].x = fmaf(a, wv.x, acc[j].x);
                acc[j].y = fmaf(a, wv.y, acc[j].y);
                acc[j].z = fmaf(a, wv.z, acc[j].z);
                acc[j].w = fmaf(a, wv.w, acc[j].w);
            }
        }
    }
    float4 bias = (cg < 64) ? ((const float4*)bmu)[cg >> 2] : ((const float4*)bls)[(cg - 64) >> 2];
    #pragma unroll
    for (int j = 0; j < 4; j++) {
        int row = r0 + rb + 8 * j;
        if (row < N_NODES) {
            float4 v = acc[j];
            v.x += bias.x; v.y += bias.y; v.z += bias.z; v.w += bias.w;
            float* dst = (cg < 64)
                ? out + (size_t)row * 64 + cg
                : out + (size_t)N_NODES * 64 + (size_t)row * 64 + (cg - 64);
            *(float4*)dst = v;
        }
    }
}

// ---------------- launch ----------------

extern "C" void kernel_launch(void* const* d_in, const int* in_sizes, int n_in,
                              void* d_out, int out_size, void* d_ws, size_t ws_size,
                              hipStream_t stream) {
    const float* x   = (const float*)d_in[0];
    const int*  eidx = (const int*)d_in[1];
    const float* W1  = (const float*)d_in[2];
    const float* b1  = (const float*)d_in[3];
    const float* Wmu = (const float*)d_in[4];
    const float* bmu = (const float*)d_in[5];
    const float* Wls = (const float*)d_in[6];
    const float* bls = (const float*)d_in[7];
    float* out = (float*)d_out;
    const int* e_src = eidx;
    const int* e_dst = eidx + N_EDGES;

    char* ws = (char*)d_ws;
    size_t off = 0;
    auto alloc = [&](size_t n) -> void* {
        void* p = ws + off;
        off += (n + 255) & ~(size_t)255;
        return p;
    };
    int*    deg       = (int*)alloc((size_t)N_NODES * sizeof(int));
    float*  dinv      = (float*)alloc((size_t)N_NODES * sizeof(float));
    int*    excl      = (int*)alloc((size_t)N_NODES * sizeof(int));
    int*    bsum      = (int*)alloc(1024 * sizeof(int));
    int*    boff      = (int*)alloc(1024 * sizeof(int));
    int*    row_start = (int*)alloc((size_t)N_NODES * sizeof(int));
    int*    cursor    = (int*)alloc((size_t)N_NODES * sizeof(int));
    int*    csr_src   = (int*)alloc((size_t)N_EDGES * sizeof(int));
    __half* xh        = (__half*)alloc((size_t)N_NODES * IN_CH * sizeof(__half));
    __half* bufA      = (__half*)alloc((size_t)N_NODES * HID * sizeof(__half));  // y1, then h
    __half* bufB      = (__half*)alloc((size_t)N_NODES * HID * sizeof(__half));  // y2

    const int NBLK_N = (N_NODES + 255) / 256;       // 391
    const int NBLK_E = (N_EDGES + 255) / 256;       // 6250
    const int NB_SCAN = (N_NODES + SCAN_T - 1) / SCAN_T;  // 98
    const int NCAST = (N_NODES * IN_CH / 4 + 255) / 256;

    hipLaunchKernelGGL(k_init_deg, dim3(NBLK_N), dim3(256), 0, stream, deg);
    hipLaunchKernelGGL(k_degree, dim3(NBLK_E), dim3(256), 0, stream, e_dst, deg);
    hipLaunchKernelGGL(k_cast_f2h, dim3(NCAST), dim3(256), 0, stream, x, xh, N_NODES * IN_CH / 4);
    hipLaunchKernelGGL(k_dinv, dim3(NBLK_N), dim3(256), 0, stream, deg, dinv);
    hipLaunchKernelGGL(k_scan_local, dim3(NB_SCAN), dim3(SCAN_T), 0, stream, deg, excl, bsum, N_NODES);
    hipLaunchKernelGGL(k_scan_sums, dim3(1), dim3(128), 0, stream, bsum, boff, NB_SCAN);
    hipLaunchKernelGGL(k_scan_add, dim3(NBLK_N), dim3(256), 0, stream, excl, boff, row_start, cursor, N_NODES);
    hipLaunchKernelGGL(k_fill_edges, dim3(NBLK_E), dim3(256), 0, stream, e_src, e_dst, cursor, csr_src);
    // layer 1: y1 = A @ x ; h = relu_norm(relu(y1 @ W1 + b1)) in-place in bufA
    hipLaunchKernelGGL(k_agg, dim3(N_NODES / 4), dim3(256), 0, stream, xh, bufA, csr_src, row_start, deg, dinv);
    hipLaunchKernelGGL(k_gemm1, dim3((N_NODES + 31) / 32), dim3(256), 0, stream, bufA, W1, b1);
    // layers 2+3 share one aggregation: y2 = A @ h
    hipLaunchKernelGGL(k_agg, dim3(N_NODES / 4), dim3(256), 0, stream, bufA, bufB, csr_src, row_start, deg, dinv);
    hipLaunchKernelGGL(k_gemm2, dim3((N_NODES + 31) / 32), dim3(256), 0, stream, bufB, Wmu, Wls, bmu, bls, out);
}

// Round 4
// 492.122 us; speedup vs baseline: 1.3372x; 1.1051x over previous
//
#include <hip/hip_runtime.h>
#include <hip/hip_fp16.h>

#define N_NODES 100000
#define IN_CH 128
#define OUT_CH 64
#define HID 128
#define N_EDGES 1600000

#define NBUCK 196          // dst >> 9, max 99999>>9 = 195
#define BBLK  256          // binning blocks
#define CHUNK (N_EDGES / BBLK)  // 6250 edges per binning block
#define NH    (NBUCK * BBLK)    // 50176 histogram entries

// ---------------- generic zero ----------------

__global__ void k_zero(int* __restrict__ p, int n) {
    int i = blockIdx.x * blockDim.x + threadIdx.x;
    if (i < n) p[i] = 0;
}

// ---------------- pass 1: per-node degree + per-(bucket,block) histogram ----------------

__global__ __launch_bounds__(256) void k_hist(const int* __restrict__ dst, int* __restrict__ deg,
                                              int* __restrict__ hist) {
    __shared__ int lh[NBUCK];
    int t = threadIdx.x;
    int blk = blockIdx.x;
    if (t < NBUCK) lh[t] = 0;
    __syncthreads();
    int base = blk * CHUNK;
    for (int i = base + t; i < base + CHUNK; i += 256) {
        int d = dst[i];
        atomicAdd(&deg[d], 1);
        atomicAdd(&lh[d >> 9], 1);
    }
    __syncthreads();
    if (t < NBUCK) hist[t * BBLK + blk] = lh[t];
}

__global__ void k_dinv(const int* __restrict__ deg, float* __restrict__ dinv) {
    int i = blockIdx.x * blockDim.x + threadIdx.x;
    if (i < N_NODES) dinv[i] = rsqrtf((float)(deg[i] + 1));  // +1 self loop
}

// ---------------- hierarchical exclusive scan ----------------

#define SCAN_T 1024
__global__ void k_scan_local(const int* __restrict__ in, int* __restrict__ excl,
                             int* __restrict__ bsum, int n) {
    __shared__ int tmp[SCAN_T];
    int t = threadIdx.x;
    int i = blockIdx.x * SCAN_T + t;
    int v = (i < n) ? in[i] : 0;
    tmp[t] = v;
    __syncthreads();
    for (int off = 1; off < SCAN_T; off <<= 1) {
        int u = (t >= off) ? tmp[t - off] : 0;
        __syncthreads();
        tmp[t] += u;
        __syncthreads();
    }
    if (i < n) excl[i] = tmp[t] - v;
    if (t == SCAN_T - 1) bsum[blockIdx.x] = tmp[t];
}

__global__ void k_scan_sums(const int* __restrict__ bsum, int* __restrict__ boff, int nb) {
    __shared__ int tmp[128];
    int t = threadIdx.x;
    int v = (t < nb) ? bsum[t] : 0;
    tmp[t] = v;
    __syncthreads();
    for (int off = 1; off < 128; off <<= 1) {
        int u = (t >= off) ? tmp[t - off] : 0;
        __syncthreads();
        tmp[t] += u;
        __syncthreads();
    }
    if (t < nb) boff[t] = tmp[t] - v;
}

__global__ void k_scan_add2(const int* __restrict__ excl, const int* __restrict__ boff,
                            int* __restrict__ out1, int* __restrict__ out2, int n) {
    int i = blockIdx.x * blockDim.x + threadIdx.x;
    if (i < n) {
        int v = excl[i] + boff[i / SCAN_T];
        out1[i] = v;
        out2[i] = v;
    }
}

__global__ void k_scan_add1(const int* __restrict__ excl, const int* __restrict__ boff,
                            int* __restrict__ out, int n) {
    int i = blockIdx.x * blockDim.x + threadIdx.x;
    if (i < n) out[i] = excl[i] + boff[i / SCAN_T];
}

// ---------------- pass 3: scatter edges into bucket-partitioned array ----------------

__global__ __launch_bounds__(256) void k_binscatter(const int* __restrict__ src,
                                                    const int* __restrict__ dst,
                                                    const int* __restrict__ off,
                                                    int2* __restrict__ binned) {
    __shared__ int loff[NBUCK];
    int t = threadIdx.x;
    int blk = blockIdx.x;
    if (t < NBUCK) loff[t] = off[t * BBLK + blk];
    __syncthreads();
    int base = blk * CHUNK;
    for (int i = base + t; i < base + CHUNK; i += 256) {
        int d = dst[i];
        int s = src[i];
        int pos = atomicAdd(&loff[d >> 9], 1);
        binned[pos] = make_int2(s, d);
    }
}

// ---------------- pass 4: fill CSR from binned edges (one block per bucket, L2-local) ------

__global__ __launch_bounds__(256) void k_fill_binned(const int2* __restrict__ binned,
                                                     const int* __restrict__ off,
                                                     int* __restrict__ cursor,
                                                     int* __restrict__ csr_src) {
    int b = blockIdx.x;
    int start = off[b * BBLK];
    int end = (b + 1 < NBUCK) ? off[(b + 1) * BBLK] : N_EDGES;
    for (int i = start + threadIdx.x; i < end; i += 256) {
        int2 e = binned[i];
        int p = atomicAdd(&cursor[e.y], 1);
        csr_src[p] = e.x;
    }
}

// ---------------- fp32 -> fp16 cast for the gather-side feature matrix ----------------

__global__ __launch_bounds__(256) void k_cast_f2h(const float* __restrict__ in,
                                                  __half* __restrict__ out, int n4) {
    int i = blockIdx.x * blockDim.x + threadIdx.x;
    if (i < n4) {
        float4 v = ((const float4*)in)[i];
        ((__half2*)out)[2 * i]     = __floats2half2_rn(v.x, v.y);
        ((__half2*)out)[2 * i + 1] = __floats2half2_rn(v.z, v.w);
    }
}

// ---------------- aggregation: y[w] = dinv[w] * ( dinv[w]*x[w] + sum_e dinv[s]*x[s] ) --------
// fp16 rows (256B), f32 accumulate. one wave per node; lane l holds channels 2l,2l+1.

__global__ __launch_bounds__(256) void k_agg(const __half* __restrict__ in, __half* __restrict__ out,
                                             const int* __restrict__ csr_src,
                                             const int* __restrict__ row_start,
                                             const int* __restrict__ deg,
                                             const float* __restrict__ dinv) {
    int w = (blockIdx.x * 256 + threadIdx.x) >> 6;
    int lane = threadIdx.x & 63;
    if (w >= N_NODES) return;
    int beg = row_start[w];
    int cnt = deg[w];
    float di = dinv[w];
    // self-loop term: coef = dinv[w]^2 (outer di applied at the end)
    float2 xv = __half22float2(((const __half2*)(in + (size_t)w * 128))[lane]);
    float2 acc = make_float2(di * xv.x, di * xv.y);
    int j = 0;
    for (; j + 7 < cnt; j += 8) {
        int s0 = csr_src[beg + j];
        int s1 = csr_src[beg + j + 1];
        int s2 = csr_src[beg + j + 2];
        int s3 = csr_src[beg + j + 3];
        int s4 = csr_src[beg + j + 4];
        int s5 = csr_src[beg + j + 5];
        int s6 = csr_src[beg + j + 6];
        int s7 = csr_src[beg + j + 7];
        float w0 = dinv[s0], w1 = dinv[s1], w2 = dinv[s2], w3 = dinv[s3];
        float w4 = dinv[s4], w5 = dinv[s5], w6 = dinv[s6], w7 = dinv[s7];
        float2 v0 = __half22float2(((const __half2*)(in + (size_t)s0 * 128))[lane]);
        float2 v1 = __half22float2(((const __half2*)(in + (size_t)s1 * 128))[lane]);
        float2 v2 = __half22float2(((const __half2*)(in + (size_t)s2 * 128))[lane]);
        float2 v3 = __half22float2(((const __half2*)(in + (size_t)s3 * 128))[lane]);
        float2 v4 = __half22float2(((const __half2*)(in + (size_t)s4 * 128))[lane]);
        float2 v5 = __half22float2(((const __half2*)(in + (size_t)s5 * 128))[lane]);
        float2 v6 = __half22float2(((const __half2*)(in + (size_t)s6 * 128))[lane]);
        float2 v7 = __half22float2(((const __half2*)(in + (size_t)s7 * 128))[lane]);
        acc.x += w0 * v0.x + w1 * v1.x + w2 * v2.x + w3 * v3.x
               + w4 * v4.x + w5 * v5.x + w6 * v6.x + w7 * v7.x;
        acc.y += w0 * v0.y + w1 * v1.y + w2 * v2.y + w3 * v3.y
               + w4 * v4.y + w5 * v5.y + w6 * v6.y + w7 * v7.y;
    }
    for (; j + 3 < cnt; j += 4) {
        int s0 = csr_src[beg + j];
        int s1 = csr_src[beg + j + 1];
        int s2 = csr_src[beg + j + 2];
        int s3 = csr_src[beg + j + 3];
        float w0 = dinv[s0], w1 = dinv[s1], w2 = dinv[s2], w3 = dinv[s3];
        float2 v0 = __half22float2(((const __half2*)(in + (size_t)s0 * 128))[lane]);
        float2 v1 = __half22float2(((const __half2*)(in + (size_t)s1 * 128))[lane]);
        float2 v2 = __half22float2(((const __half2*)(in + (size_t)s2 * 128))[lane]);
        float2 v3 = __half22float2(((const __half2*)(in + (size_t)s3 * 128))[lane]);
        acc.x += w0 * v0.x + w1 * v1.x + w2 * v2.x + w3 * v3.x;
        acc.y += w0 * v0.y + w1 * v1.y + w2 * v2.y + w3 * v3.y;
    }
    for (; j < cnt; j++) {
        int s0 = csr_src[beg + j];
        float w0 = dinv[s0];
        float2 v0 = __half22float2(((const __half2*)(in + (size_t)s0 * 128))[lane]);
        acc.x += w0 * v0.x;
        acc.y += w0 * v0.y;
    }
    ((__half2*)(out + (size_t)w * 128))[lane] = __floats2half2_rn(di * acc.x, di * acc.y);
}

// ---------------- GEMM1: buf = relu_normalize(relu(buf @ W1 + b1)) in-place (fp16 io) ----------------

__global__ __launch_bounds__(256) void k_gemm1(__half* __restrict__ buf, const float* __restrict__ W,
                                               const float* __restrict__ b) {
    __shared__ float Wl[64 * 128];
    __shared__ float Al[32 * 128];
    int t = threadIdx.x;
    int r0 = blockIdx.x * 32;
    for (int i = t; i < 32 * 16; i += 256) {  // 32 rows * 16 chunks of 8 halves (16B)
        int rr = i >> 4, cc = i & 15;
        int gr = r0 + rr;
        float2 f0 = make_float2(0.f, 0.f), f1 = f0, f2 = f0, f3 = f0;
        if (gr < N_NODES) {
            const __half2* p = (const __half2*)(buf + (size_t)gr * 128) + cc * 4;
            f0 = __half22float2(p[0]);
            f1 = __half22float2(p[1]);
            f2 = __half22float2(p[2]);
            f3 = __half22float2(p[3]);
        }
        float* dp = &Al[rr * 128 + cc * 8];
        *(float4*)(dp)     = make_float4(f0.x, f0.y, f1.x, f1.y);
        *(float4*)(dp + 4) = make_float4(f2.x, f2.y, f3.x, f3.y);
    }
    int cg = (t & 31) << 2;
    int rb = t >> 5;
    float4 acc[4];
    acc[0] = acc[1] = acc[2] = acc[3] = make_float4(0.f, 0.f, 0.f, 0.f);
    for (int p = 0; p < 2; p++) {
        __syncthreads();  // Al visible (p=0); Wl no longer read (p=1)
        for (int i = t; i < 64 * 32; i += 256) {  // 64 W-rows * 32 float4
            int kk = i >> 5, cc = i & 31;
            ((float4*)&Wl[kk * 128])[cc] = ((const float4*)&W[(size_t)(p * 64 + kk) * 128])[cc];
        }
        __syncthreads();
        #pragma unroll 4
        for (int k2 = 0; k2 < 64; k2++) {
            float4 wv = *(float4*)&Wl[k2 * 128 + cg];
            int kg = p * 64 + k2;
            #pragma unroll
            for (int j = 0; j < 4; j++) {
                float a = Al[(rb + 8 * j) * 128 + kg];
                acc[j].x = fmaf(a, wv.x, acc[j].x);
                acc[j].y = fmaf(a, wv.y, acc[j].y);
                acc[j].z = fmaf(a, wv.z, acc[j].z);
                acc[j].w = fmaf(a, wv.w, acc[j].w);
            }
        }
    }
    float4 bias = *(const float4*)&b[cg];
    #pragma unroll
    for (int j = 0; j < 4; j++) {
        int row = r0 + rb + 8 * j;
        float4 v = acc[j];
        v.x = fmaxf(v.x + bias.x, 0.f);
        v.y = fmaxf(v.y + bias.y, 0.f);
        v.z = fmaxf(v.z + bias.z, 0.f);
        v.w = fmaxf(v.w + bias.w, 0.f);
        float ssq = v.x * v.x + v.y * v.y + v.z * v.z + v.w * v.w;
        #pragma unroll
        for (int m = 1; m < 32; m <<= 1) ssq += __shfl_xor(ssq, m, 64);
        float s = 1.0f / fmaxf(sqrtf(ssq), 1e-12f);
        if (row < N_NODES) {
            __half2* dp = (__half2*)(buf + (size_t)row * 128 + cg);
            dp[0] = __floats2half2_rn(v.x * s, v.y * s);  // second relu is a no-op (all >= 0)
            dp[1] = __floats2half2_rn(v.z * s, v.w * s);
        }
    }
}

// ---------------- GEMM2: out = [ y2@Wmu+bmu | y2@Wls+bls ] split-written to d_out ----------------

__global__ __launch_bounds__(256) void k_gemm2(const __half* __restrict__ bufin,
                                               const float* __restrict__ Wmu,
                                               const float* __restrict__ Wls,
                                               const float* __restrict__ bmu,
                                               const float* __restrict__ bls,
                                               float* __restrict__ out) {
    __shared__ float Wl[64 * 128];
    __shared__ float Al[32 * 128];
    int t = threadIdx.x;
    int r0 = blockIdx.x * 32;
    for (int i = t; i < 32 * 16; i += 256) {
        int rr = i >> 4, cc = i & 15;
        int gr = r0 + rr;
        float2 f0 = make_float2(0.f, 0.f), f1 = f0, f2 = f0, f3 = f0;
        if (gr < N_NODES) {
            const __half2* p = (const __half2*)(bufin + (size_t)gr * 128) + cc * 4;
            f0 = __half22float2(p[0]);
            f1 = __half22float2(p[1]);
            f2 = __half22float2(p[2]);
            f3 = __half22float2(p[3]);
        }
        float* dp = &Al[rr * 128 + cc * 8];
        *(float4*)(dp)     = make_float4(f0.x, f0.y, f1.x, f1.y);
        *(float4*)(dp + 4) = make_float4(f2.x, f2.y, f3.x, f3.y);
    }
    int cg = (t & 31) << 2;
    int rb = t >> 5;
    float4 acc[4];
    acc[0] = acc[1] = acc[2] = acc[3] = make_float4(0.f, 0.f, 0.f, 0.f);
    for (int p = 0; p < 2; p++) {
        __syncthreads();
        for (int i = t; i < 64 * 16; i += 256) {  // 64 W-rows * 16 float4 per half
            int kk = i >> 4, c4 = i & 15;
            ((float4*)&Wl[kk * 128])[c4]      = ((const float4*)&Wmu[(size_t)(p * 64 + kk) * 64])[c4];
            ((float4*)&Wl[kk * 128 + 64])[c4] = ((const float4*)&Wls[(size_t)(p * 64 + kk) * 64])[c4];
        }
        __syncthreads();
        #pragma unroll 4
        for (int k2 = 0; k2 < 64; k2++) {
            float4 wv = *(float4*)&Wl[k2 * 128 + cg];
            int kg = p * 64 + k2;
            #pragma unroll
            for (int j = 0; j < 4; j++) {
                float a = Al[(rb + 8 * j) * 128 + kg];
                acc[j].x = fmaf(a, wv.x, acc[j].x);
                acc[j].y = fmaf(a, wv.y, acc[j].y);
                acc[j].z = fmaf(a, wv.z, acc[j].z);
                acc[j].w = fmaf(a, wv.w, acc[j].w);
            }
        }
    }
    float4 bias = (cg < 64) ? ((const float4*)bmu)[cg >> 2] : ((const float4*)bls)[(cg - 64) >> 2];
    #pragma unroll
    for (int j = 0; j < 4; j++) {
        int row = r0 + rb + 8 * j;
        if (row < N_NODES) {
            float4 v = acc[j];
            v.x += bias.x; v.y += bias.y; v.z += bias.z; v.w += bias.w;
            float* dst = (cg < 64)
                ? out + (size_t)row * 64 + cg
                : out + (size_t)N_NODES * 64 + (size_t)row * 64 + (cg - 64);
            *(float4*)dst = v;
        }
    }
}

// ---------------- launch ----------------

extern "C" void kernel_launch(void* const* d_in, const int* in_sizes, int n_in,
                              void* d_out, int out_size, void* d_ws, size_t ws_size,
                              hipStream_t stream) {
    const float* x   = (const float*)d_in[0];
    const int*  eidx = (const int*)d_in[1];
    const float* W1  = (const float*)d_in[2];
    const float* b1  = (const float*)d_in[3];
    const float* Wmu = (const float*)d_in[4];
    const float* bmu = (const float*)d_in[5];
    const float* Wls = (const float*)d_in[6];
    const float* bls = (const float*)d_in[7];
    float* out = (float*)d_out;
    const int* e_src = eidx;
    const int* e_dst = eidx + N_EDGES;

    char* ws = (char*)d_ws;
    size_t off_b = 0;
    auto alloc = [&](size_t n) -> void* {
        void* p = ws + off_b;
        off_b += (n + 255) & ~(size_t)255;
        return p;
    };
    int*    deg       = (int*)alloc((size_t)N_NODES * sizeof(int));
    float*  dinv      = (float*)alloc((size_t)N_NODES * sizeof(float));
    int*    excl      = (int*)alloc((size_t)N_NODES * sizeof(int));
    int*    bsum      = (int*)alloc(1024 * sizeof(int));
    int*    boff      = (int*)alloc(1024 * sizeof(int));
    int*    row_start = (int*)alloc((size_t)N_NODES * sizeof(int));
    int*    cursor    = (int*)alloc((size_t)N_NODES * sizeof(int));
    int*    hist      = (int*)alloc((size_t)NH * sizeof(int));
    int*    excl2     = (int*)alloc((size_t)NH * sizeof(int));
    int*    bsum2     = (int*)alloc(1024 * sizeof(int));
    int*    boff2     = (int*)alloc(1024 * sizeof(int));
    int*    offs      = (int*)alloc((size_t)NH * sizeof(int));
    int*    csr_src   = (int*)alloc((size_t)N_EDGES * sizeof(int));
    int2*   binned    = (int2*)alloc((size_t)N_EDGES * sizeof(int2));
    __half* xh        = (__half*)alloc((size_t)N_NODES * IN_CH * sizeof(__half));
    __half* bufA      = (__half*)alloc((size_t)N_NODES * HID * sizeof(__half));  // y1, then h
    __half* bufB      = (__half*)alloc((size_t)N_NODES * HID * sizeof(__half));  // y2

    const int NBLK_N = (N_NODES + 255) / 256;             // 391
    const int NB_SCAN  = (N_NODES + SCAN_T - 1) / SCAN_T; // 98
    const int NB_SCAN2 = (NH + SCAN_T - 1) / SCAN_T;      // 49
    const int NCAST = (N_NODES * IN_CH / 4 + 255) / 256;

    hipLaunchKernelGGL(k_zero, dim3(NBLK_N), dim3(256), 0, stream, deg, N_NODES);
    hipLaunchKernelGGL(k_zero, dim3((NH + 255) / 256), dim3(256), 0, stream, hist, NH);
    hipLaunchKernelGGL(k_cast_f2h, dim3(NCAST), dim3(256), 0, stream, x, xh, N_NODES * IN_CH / 4);
    // pass 1: degree + bucket histogram
    hipLaunchKernelGGL(k_hist, dim3(BBLK), dim3(256), 0, stream, e_dst, deg, hist);
    hipLaunchKernelGGL(k_dinv, dim3(NBLK_N), dim3(256), 0, stream, deg, dinv);
    // scan degrees -> row_start / cursor
    hipLaunchKernelGGL(k_scan_local, dim3(NB_SCAN), dim3(SCAN_T), 0, stream, deg, excl, bsum, N_NODES);
    hipLaunchKernelGGL(k_scan_sums, dim3(1), dim3(128), 0, stream, bsum, boff, NB_SCAN);
    hipLaunchKernelGGL(k_scan_add2, dim3(NBLK_N), dim3(256), 0, stream, excl, boff, row_start, cursor, N_NODES);
    // scan histogram -> per-(bucket,block) offsets
    hipLaunchKernelGGL(k_scan_local, dim3(NB_SCAN2), dim3(SCAN_T), 0, stream, hist, excl2, bsum2, NH);
    hipLaunchKernelGGL(k_scan_sums, dim3(1), dim3(128), 0, stream, bsum2, boff2, NB_SCAN2);
    hipLaunchKernelGGL(k_scan_add1, dim3((NH + 255) / 256), dim3(256), 0, stream, excl2, boff2, offs, NH);
    // pass 3: bin edges; pass 4: L2-local CSR fill
    hipLaunchKernelGGL(k_binscatter, dim3(BBLK), dim3(256), 0, stream, e_src, e_dst, offs, binned);
    hipLaunchKernelGGL(k_fill_binned, dim3(NBUCK), dim3(256), 0, stream, binned, offs, cursor, csr_src);
    // layer 1: y1 = A @ x ; h = relu_norm(relu(y1 @ W1 + b1)) in-place in bufA
    hipLaunchKernelGGL(k_agg, dim3(N_NODES / 4), dim3(256), 0, stream, xh, bufA, csr_src, row_start, deg, dinv);
    hipLaunchKernelGGL(k_gemm1, dim3((N_NODES + 31) / 32), dim3(256), 0, stream, bufA, W1, b1);
    // layers 2+3 share one aggregation: y2 = A @ h
    hipLaunchKernelGGL(k_agg, dim3(N_NODES / 4), dim3(256), 0, stream, bufA, bufB, csr_src, row_start, deg, dinv);
    hipLaunchKernelGGL(k_gemm2, dim3((N_NODES + 31) / 32), dim3(256), 0, stream, bufB, Wmu, Wls, bmu, bls, out);
}

// Round 5
// 408.108 us; speedup vs baseline: 1.6125x; 1.2059x over previous
//
#include <hip/hip_runtime.h>
#include <hip/hip_fp16.h>

#define N_NODES 100000
#define IN_CH 128
#define OUT_CH 64
#define HID 128
#define N_EDGES 1600000

#define NBUCK 196               // dst >> 9, max 99999>>9 = 195
#define BBLK  512               // binning blocks (2 per CU)
#define CHUNK (N_EDGES / BBLK)  // 3125 edges per binning block
#define NH    (NBUCK * BBLK)    // 100352 histogram entries

// ---------------- generic zero ----------------

__global__ void k_zero(int* __restrict__ p, int n) {
    int i = blockIdx.x * blockDim.x + threadIdx.x;
    if (i < n) p[i] = 0;
}

// ---------------- pass 1: per-(bucket,block) histogram only (LDS atomics) ----------------

__global__ __launch_bounds__(256) void k_hist(const int* __restrict__ dst, int* __restrict__ hist) {
    __shared__ int lh[NBUCK];
    int t = threadIdx.x;
    int blk = blockIdx.x;
    if (t < NBUCK) lh[t] = 0;
    __syncthreads();
    int base = blk * CHUNK;
    for (int i = base + t; i < base + CHUNK; i += 256) {
        atomicAdd(&lh[dst[i] >> 9], 1);
    }
    __syncthreads();
    if (t < NBUCK) hist[t * BBLK + blk] = lh[t];
}

// ---------------- hierarchical exclusive scan (hist only) ----------------

#define SCAN_T 1024
__global__ void k_scan_local(const int* __restrict__ in, int* __restrict__ excl,
                             int* __restrict__ bsum, int n) {
    __shared__ int tmp[SCAN_T];
    int t = threadIdx.x;
    int i = blockIdx.x * SCAN_T + t;
    int v = (i < n) ? in[i] : 0;
    tmp[t] = v;
    __syncthreads();
    for (int off = 1; off < SCAN_T; off <<= 1) {
        int u = (t >= off) ? tmp[t - off] : 0;
        __syncthreads();
        tmp[t] += u;
        __syncthreads();
    }
    if (i < n) excl[i] = tmp[t] - v;
    if (t == SCAN_T - 1) bsum[blockIdx.x] = tmp[t];
}

__global__ void k_scan_sums(const int* __restrict__ bsum, int* __restrict__ boff, int nb) {
    __shared__ int tmp[128];
    int t = threadIdx.x;
    int v = (t < nb) ? bsum[t] : 0;
    tmp[t] = v;
    __syncthreads();
    for (int off = 1; off < 128; off <<= 1) {
        int u = (t >= off) ? tmp[t - off] : 0;
        __syncthreads();
        tmp[t] += u;
        __syncthreads();
    }
    if (t < nb) boff[t] = tmp[t] - v;
}

__global__ void k_scan_add1(const int* __restrict__ excl, const int* __restrict__ boff,
                            int* __restrict__ out, int n) {
    int i = blockIdx.x * blockDim.x + threadIdx.x;
    if (i < n) out[i] = excl[i] + boff[i / SCAN_T];
}

// ---------------- pass 2: scatter edges into bucket-partitioned array ----------------

__global__ __launch_bounds__(256) void k_binscatter(const int* __restrict__ src,
                                                    const int* __restrict__ dst,
                                                    const int* __restrict__ off,
                                                    int2* __restrict__ binned) {
    __shared__ int loff[NBUCK];
    int t = threadIdx.x;
    int blk = blockIdx.x;
    if (t < NBUCK) loff[t] = off[t * BBLK + blk];
    __syncthreads();
    int base = blk * CHUNK;
    for (int i = base + t; i < base + CHUNK; i += 256) {
        int d = dst[i];
        int s = src[i];
        int pos = atomicAdd(&loff[d >> 9], 1);
        binned[pos] = make_int2(s, d);
    }
}

// ---------------- pass 3: per-bucket degree/scan/fill entirely in LDS ----------------
// one block per bucket (512 nodes, contiguous edge window). Produces row_start, deg,
// dinv, csr_src with ZERO global atomics.

__global__ __launch_bounds__(256) void k_bucket(const int2* __restrict__ binned,
                                                const int* __restrict__ off,
                                                int* __restrict__ row_start,
                                                int* __restrict__ deg,
                                                float* __restrict__ dinv,
                                                int* __restrict__ csr_src) {
    __shared__ int cnt[512];
    __shared__ int ps[256];
    __shared__ int cur[512];
    int b = blockIdx.x;
    int t = threadIdx.x;
    int start = off[b * BBLK];
    int end = (b + 1 < NBUCK) ? off[(b + 1) * BBLK] : N_EDGES;
    cnt[t] = 0;
    cnt[t + 256] = 0;
    __syncthreads();
    for (int i = start + t; i < end; i += 256) {
        atomicAdd(&cnt[binned[i].y & 511], 1);
    }
    __syncthreads();
    // exclusive scan of 512 counters: pair-sum -> 256-wide Hillis-Steele -> expand
    int a0 = cnt[2 * t], a1 = cnt[2 * t + 1];
    ps[t] = a0 + a1;
    __syncthreads();
    for (int o = 1; o < 256; o <<= 1) {
        int u = (t >= o) ? ps[t - o] : 0;
        __syncthreads();
        ps[t] += u;
        __syncthreads();
    }
    int pe = ps[t] - (a0 + a1);  // exclusive prefix of pair 2t
    int e0 = start + pe;
    int e1 = e0 + a0;
    cur[2 * t] = e0;
    cur[2 * t + 1] = e1;
    int node0 = (b << 9) + 2 * t;
    if (node0 < N_NODES) {
        row_start[node0] = e0;
        deg[node0] = a0;
        dinv[node0] = rsqrtf((float)(a0 + 1));
    }
    if (node0 + 1 < N_NODES) {
        row_start[node0 + 1] = e1;
        deg[node0 + 1] = a1;
        dinv[node0 + 1] = rsqrtf((float)(a1 + 1));
    }
    __syncthreads();
    for (int i = start + t; i < end; i += 256) {
        int2 e = binned[i];
        int p = atomicAdd(&cur[e.y & 511], 1);
        csr_src[p] = e.x;
    }
}

// ---------------- fp32 -> fp16 cast for the gather-side feature matrix ----------------

__global__ __launch_bounds__(256) void k_cast_f2h(const float* __restrict__ in,
                                                  __half* __restrict__ out, int n4) {
    int i = blockIdx.x * blockDim.x + threadIdx.x;
    if (i < n4) {
        float4 v = ((const float4*)in)[i];
        ((__half2*)out)[2 * i]     = __floats2half2_rn(v.x, v.y);
        ((__half2*)out)[2 * i + 1] = __floats2half2_rn(v.z, v.w);
    }
}

// ---------------- aggregation: y[w] = dinv[w] * ( dinv[w]*x[w] + sum_e dinv[s]*x[s] ) --------
// fp16 rows (256B), f32 accumulate. one wave per node; lane l holds channels 2l,2l+1.

__global__ __launch_bounds__(256) void k_agg(const __half* __restrict__ in, __half* __restrict__ out,
                                             const int* __restrict__ csr_src,
                                             const int* __restrict__ row_start,
                                             const int* __restrict__ deg,
                                             const float* __restrict__ dinv) {
    int w = (blockIdx.x * 256 + threadIdx.x) >> 6;
    int lane = threadIdx.x & 63;
    if (w >= N_NODES) return;
    int beg = row_start[w];
    int cnt = deg[w];
    float di = dinv[w];
    // self-loop term: coef = dinv[w]^2 (outer di applied at the end)
    float2 xv = __half22float2(((const __half2*)(in + (size_t)w * 128))[lane]);
    float2 acc = make_float2(di * xv.x, di * xv.y);
    int j = 0;
    for (; j + 7 < cnt; j += 8) {
        int s0 = csr_src[beg + j];
        int s1 = csr_src[beg + j + 1];
        int s2 = csr_src[beg + j + 2];
        int s3 = csr_src[beg + j + 3];
        int s4 = csr_src[beg + j + 4];
        int s5 = csr_src[beg + j + 5];
        int s6 = csr_src[beg + j + 6];
        int s7 = csr_src[beg + j + 7];
        float w0 = dinv[s0], w1 = dinv[s1], w2 = dinv[s2], w3 = dinv[s3];
        float w4 = dinv[s4], w5 = dinv[s5], w6 = dinv[s6], w7 = dinv[s7];
        float2 v0 = __half22float2(((const __half2*)(in + (size_t)s0 * 128))[lane]);
        float2 v1 = __half22float2(((const __half2*)(in + (size_t)s1 * 128))[lane]);
        float2 v2 = __half22float2(((const __half2*)(in + (size_t)s2 * 128))[lane]);
        float2 v3 = __half22float2(((const __half2*)(in + (size_t)s3 * 128))[lane]);
        float2 v4 = __half22float2(((const __half2*)(in + (size_t)s4 * 128))[lane]);
        float2 v5 = __half22float2(((const __half2*)(in + (size_t)s5 * 128))[lane]);
        float2 v6 = __half22float2(((const __half2*)(in + (size_t)s6 * 128))[lane]);
        float2 v7 = __half22float2(((const __half2*)(in + (size_t)s7 * 128))[lane]);
        acc.x += w0 * v0.x + w1 * v1.x + w2 * v2.x + w3 * v3.x
               + w4 * v4.x + w5 * v5.x + w6 * v6.x + w7 * v7.x;
        acc.y += w0 * v0.y + w1 * v1.y + w2 * v2.y + w3 * v3.y
               + w4 * v4.y + w5 * v5.y + w6 * v6.y + w7 * v7.y;
    }
    for (; j + 3 < cnt; j += 4) {
        int s0 = csr_src[beg + j];
        int s1 = csr_src[beg + j + 1];
        int s2 = csr_src[beg + j + 2];
        int s3 = csr_src[beg + j + 3];
        float w0 = dinv[s0], w1 = dinv[s1], w2 = dinv[s2], w3 = dinv[s3];
        float2 v0 = __half22float2(((const __half2*)(in + (size_t)s0 * 128))[lane]);
        float2 v1 = __half22float2(((const __half2*)(in + (size_t)s1 * 128))[lane]);
        float2 v2 = __half22float2(((const __half2*)(in + (size_t)s2 * 128))[lane]);
        float2 v3 = __half22float2(((const __half2*)(in + (size_t)s3 * 128))[lane]);
        acc.x += w0 * v0.x + w1 * v1.x + w2 * v2.x + w3 * v3.x;
        acc.y += w0 * v0.y + w1 * v1.y + w2 * v2.y + w3 * v3.y;
    }
    for (; j < cnt; j++) {
        int s0 = csr_src[beg + j];
        float w0 = dinv[s0];
        float2 v0 = __half22float2(((const __half2*)(in + (size_t)s0 * 128))[lane]);
        acc.x += w0 * v0.x;
        acc.y += w0 * v0.y;
    }
    ((__half2*)(out + (size_t)w * 128))[lane] = __floats2half2_rn(di * acc.x, di * acc.y);
}

// ---------------- GEMM1: buf = relu_normalize(relu(buf @ W1 + b1)) in-place (fp16 io) ----------------

__global__ __launch_bounds__(256) void k_gemm1(__half* __restrict__ buf, const float* __restrict__ W,
                                               const float* __restrict__ b) {
    __shared__ float Wl[64 * 128];
    __shared__ float Al[32 * 128];
    int t = threadIdx.x;
    int r0 = blockIdx.x * 32;
    for (int i = t; i < 32 * 16; i += 256) {  // 32 rows * 16 chunks of 8 halves (16B)
        int rr = i >> 4, cc = i & 15;
        int gr = r0 + rr;
        float2 f0 = make_float2(0.f, 0.f), f1 = f0, f2 = f0, f3 = f0;
        if (gr < N_NODES) {
            const __half2* p = (const __half2*)(buf + (size_t)gr * 128) + cc * 4;
            f0 = __half22float2(p[0]);
            f1 = __half22float2(p[1]);
            f2 = __half22float2(p[2]);
            f3 = __half22float2(p[3]);
        }
        float* dp = &Al[rr * 128 + cc * 8];
        *(float4*)(dp)     = make_float4(f0.x, f0.y, f1.x, f1.y);
        *(float4*)(dp + 4) = make_float4(f2.x, f2.y, f3.x, f3.y);
    }
    int cg = (t & 31) << 2;
    int rb = t >> 5;
    float4 acc[4];
    acc[0] = acc[1] = acc[2] = acc[3] = make_float4(0.f, 0.f, 0.f, 0.f);
    for (int p = 0; p < 2; p++) {
        __syncthreads();  // Al visible (p=0); Wl no longer read (p=1)
        for (int i = t; i < 64 * 32; i += 256) {  // 64 W-rows * 32 float4
            int kk = i >> 5, cc = i & 31;
            ((float4*)&Wl[kk * 128])[cc] = ((const float4*)&W[(size_t)(p * 64 + kk) * 128])[cc];
        }
        __syncthreads();
        #pragma unroll 4
        for (int k2 = 0; k2 < 64; k2++) {
            float4 wv = *(float4*)&Wl[k2 * 128 + cg];
            int kg = p * 64 + k2;
            #pragma unroll
            for (int j = 0; j < 4; j++) {
                float a = Al[(rb + 8 * j) * 128 + kg];
                acc[j].x = fmaf(a, wv.x, acc[j].x);
                acc[j].y = fmaf(a, wv.y, acc[j].y);
                acc[j].z = fmaf(a, wv.z, acc[j].z);
                acc[j].w = fmaf(a, wv.w, acc[j].w);
            }
        }
    }
    float4 bias = *(const float4*)&b[cg];
    #pragma unroll
    for (int j = 0; j < 4; j++) {
        int row = r0 + rb + 8 * j;
        float4 v = acc[j];
        v.x = fmaxf(v.x + bias.x, 0.f);
        v.y = fmaxf(v.y + bias.y, 0.f);
        v.z = fmaxf(v.z + bias.z, 0.f);
        v.w = fmaxf(v.w + bias.w, 0.f);
        float ssq = v.x * v.x + v.y * v.y + v.z * v.z + v.w * v.w;
        #pragma unroll
        for (int m = 1; m < 32; m <<= 1) ssq += __shfl_xor(ssq, m, 64);
        float s = 1.0f / fmaxf(sqrtf(ssq), 1e-12f);
        if (row < N_NODES) {
            __half2* dp = (__half2*)(buf + (size_t)row * 128 + cg);
            dp[0] = __floats2half2_rn(v.x * s, v.y * s);  // second relu is a no-op (all >= 0)
            dp[1] = __floats2half2_rn(v.z * s, v.w * s);
        }
    }
}

// ---------------- GEMM2: out = [ y2@Wmu+bmu | y2@Wls+bls ] split-written to d_out ----------------

__global__ __launch_bounds__(256) void k_gemm2(const __half* __restrict__ bufin,
                                               const float* __restrict__ Wmu,
                                               const float* __restrict__ Wls,
                                               const float* __restrict__ bmu,
                                               const float* __restrict__ bls,
                                               float* __restrict__ out) {
    __shared__ float Wl[64 * 128];
    __shared__ float Al[32 * 128];
    int t = threadIdx.x;
    int r0 = blockIdx.x * 32;
    for (int i = t; i < 32 * 16; i += 256) {
        int rr = i >> 4, cc = i & 15;
        int gr = r0 + rr;
        float2 f0 = make_float2(0.f, 0.f), f1 = f0, f2 = f0, f3 = f0;
        if (gr < N_NODES) {
            const __half2* p = (const __half2*)(bufin + (size_t)gr * 128) + cc * 4;
            f0 = __half22float2(p[0]);
            f1 = __half22float2(p[1]);
            f2 = __half22float2(p[2]);
            f3 = __half22float2(p[3]);
        }
        float* dp = &Al[rr * 128 + cc * 8];
        *(float4*)(dp)     = make_float4(f0.x, f0.y, f1.x, f1.y);
        *(float4*)(dp + 4) = make_float4(f2.x, f2.y, f3.x, f3.y);
    }
    int cg = (t & 31) << 2;
    int rb = t >> 5;
    float4 acc[4];
    acc[0] = acc[1] = acc[2] = acc[3] = make_float4(0.f, 0.f, 0.f, 0.f);
    for (int p = 0; p < 2; p++) {
        __syncthreads();
        for (int i = t; i < 64 * 16; i += 256) {  // 64 W-rows * 16 float4 per half
            int kk = i >> 4, c4 = i & 15;
            ((float4*)&Wl[kk * 128])[c4]      = ((const float4*)&Wmu[(size_t)(p * 64 + kk) * 64])[c4];
            ((float4*)&Wl[kk * 128 + 64])[c4] = ((const float4*)&Wls[(size_t)(p * 64 + kk) * 64])[c4];
        }
        __syncthreads();
        #pragma unroll 4
        for (int k2 = 0; k2 < 64; k2++) {
            float4 wv = *(float4*)&Wl[k2 * 128 + cg];
            int kg = p * 64 + k2;
            #pragma unroll
            for (int j = 0; j < 4; j++) {
                float a = Al[(rb + 8 * j) * 128 + kg];
                acc[j].x = fmaf(a, wv.x, acc[j].x);
                acc[j].y = fmaf(a, wv.y, acc[j].y);
                acc[j].z = fmaf(a, wv.z, acc[j].z);
                acc[j].w = fmaf(a, wv.w, acc[j].w);
            }
        }
    }
    float4 bias = (cg < 64) ? ((const float4*)bmu)[cg >> 2] : ((const float4*)bls)[(cg - 64) >> 2];
    #pragma unroll
    for (int j = 0; j < 4; j++) {
        int row = r0 + rb + 8 * j;
        if (row < N_NODES) {
            float4 v = acc[j];
            v.x += bias.x; v.y += bias.y; v.z += bias.z; v.w += bias.w;
            float* dst = (cg < 64)
                ? out + (size_t)row * 64 + cg
                : out + (size_t)N_NODES * 64 + (size_t)row * 64 + (cg - 64);
            *(float4*)dst = v;
        }
    }
}

// ---------------- launch ----------------

extern "C" void kernel_launch(void* const* d_in, const int* in_sizes, int n_in,
                              void* d_out, int out_size, void* d_ws, size_t ws_size,
                              hipStream_t stream) {
    const float* x   = (const float*)d_in[0];
    const int*  eidx = (const int*)d_in[1];
    const float* W1  = (const float*)d_in[2];
    const float* b1  = (const float*)d_in[3];
    const float* Wmu = (const float*)d_in[4];
    const float* bmu = (const float*)d_in[5];
    const float* Wls = (const float*)d_in[6];
    const float* bls = (const float*)d_in[7];
    float* out = (float*)d_out;
    const int* e_src = eidx;
    const int* e_dst = eidx + N_EDGES;

    char* ws = (char*)d_ws;
    size_t off_b = 0;
    auto alloc = [&](size_t n) -> void* {
        void* p = ws + off_b;
        off_b += (n + 255) & ~(size_t)255;
        return p;
    };
    int*    deg       = (int*)alloc((size_t)N_NODES * sizeof(int));
    float*  dinv      = (float*)alloc((size_t)N_NODES * sizeof(float));
    int*    row_start = (int*)alloc((size_t)N_NODES * sizeof(int));
    int*    hist      = (int*)alloc((size_t)NH * sizeof(int));
    int*    excl2     = (int*)alloc((size_t)NH * sizeof(int));
    int*    bsum2     = (int*)alloc(1024 * sizeof(int));
    int*    boff2     = (int*)alloc(1024 * sizeof(int));
    int*    offs      = (int*)alloc((size_t)NH * sizeof(int));
    int*    csr_src   = (int*)alloc((size_t)N_EDGES * sizeof(int));
    int2*   binned    = (int2*)alloc((size_t)N_EDGES * sizeof(int2));
    __half* xh        = (__half*)alloc((size_t)N_NODES * IN_CH * sizeof(__half));
    __half* bufA      = (__half*)alloc((size_t)N_NODES * HID * sizeof(__half));  // y1, then h
    __half* bufB      = (__half*)alloc((size_t)N_NODES * HID * sizeof(__half));  // y2

    const int NB_SCAN2 = (NH + SCAN_T - 1) / SCAN_T;  // 98
    const int NCAST = (N_NODES * IN_CH / 4 + 255) / 256;

    hipLaunchKernelGGL(k_zero, dim3((NH + 255) / 256), dim3(256), 0, stream, hist, NH);
    hipLaunchKernelGGL(k_cast_f2h, dim3(NCAST), dim3(256), 0, stream, x, xh, N_NODES * IN_CH / 4);
    // pass 1: bucket histogram (LDS only)
    hipLaunchKernelGGL(k_hist, dim3(BBLK), dim3(256), 0, stream, e_dst, hist);
    // scan histogram -> per-(bucket,block) offsets
    hipLaunchKernelGGL(k_scan_local, dim3(NB_SCAN2), dim3(SCAN_T), 0, stream, hist, excl2, bsum2, NH);
    hipLaunchKernelGGL(k_scan_sums, dim3(1), dim3(128), 0, stream, bsum2, boff2, NB_SCAN2);
    hipLaunchKernelGGL(k_scan_add1, dim3((NH + 255) / 256), dim3(256), 0, stream, excl2, boff2, offs, NH);
    // pass 2: bin edges; pass 3: per-bucket LDS degree/scan/fill (no global atomics)
    hipLaunchKernelGGL(k_binscatter, dim3(BBLK), dim3(256), 0, stream, e_src, e_dst, offs, binned);
    hipLaunchKernelGGL(k_bucket, dim3(NBUCK), dim3(256), 0, stream, binned, offs, row_start, deg, dinv, csr_src);
    // layer 1: y1 = A @ x ; h = relu_norm(relu(y1 @ W1 + b1)) in-place in bufA
    hipLaunchKernelGGL(k_agg, dim3(N_NODES / 4), dim3(256), 0, stream, xh, bufA, csr_src, row_start, deg, dinv);
    hipLaunchKernelGGL(k_gemm1, dim3((N_NODES + 31) / 32), dim3(256), 0, stream, bufA, W1, b1);
    // layers 2+3 share one aggregation: y2 = A @ h
    hipLaunchKernelGGL(k_agg, dim3(N_NODES / 4), dim3(256), 0, stream, bufA, bufB, csr_src, row_start, deg, dinv);
    hipLaunchKernelGGL(k_gemm2, dim3((N_NODES + 31) / 32), dim3(256), 0, stream, bufB, Wmu, Wls, bmu, bls, out);
}

// Round 6
// 364.159 us; speedup vs baseline: 1.8071x; 1.1207x over previous
//
#include <hip/hip_runtime.h>
#include <hip/hip_fp16.h>

#define N_NODES 100000
#define IN_CH 128
#define OUT_CH 64
#define HID 128
#define N_EDGES 1600000

#define NBUCK 196               // dst >> 9, max 99999>>9 = 195
#define BBLK  512               // binning blocks (2 per CU)
#define CHUNK (N_EDGES / BBLK)  // 3125 edges per binning block
#define NH    (NBUCK * BBLK)    // 100352 histogram entries

typedef _Float16 half8 __attribute__((ext_vector_type(8)));
typedef float floatx4 __attribute__((ext_vector_type(4)));

// ---------------- pass 1: per-(bucket,block) histogram (LDS atomics; fully overwrites hist) ----

__global__ __launch_bounds__(256) void k_hist(const int* __restrict__ dst, int* __restrict__ hist) {
    __shared__ int lh[NBUCK];
    int t = threadIdx.x;
    int blk = blockIdx.x;
    if (t < NBUCK) lh[t] = 0;
    __syncthreads();
    int base = blk * CHUNK;
    for (int i = base + t; i < base + CHUNK; i += 256) {
        atomicAdd(&lh[dst[i] >> 9], 1);
    }
    __syncthreads();
    if (t < NBUCK) hist[t * BBLK + blk] = lh[t];
}

// ---------------- hierarchical exclusive scan (hist only) ----------------

#define SCAN_T 1024
__global__ void k_scan_local(const int* __restrict__ in, int* __restrict__ excl,
                             int* __restrict__ bsum, int n) {
    __shared__ int tmp[SCAN_T];
    int t = threadIdx.x;
    int i = blockIdx.x * SCAN_T + t;
    int v = (i < n) ? in[i] : 0;
    tmp[t] = v;
    __syncthreads();
    for (int off = 1; off < SCAN_T; off <<= 1) {
        int u = (t >= off) ? tmp[t - off] : 0;
        __syncthreads();
        tmp[t] += u;
        __syncthreads();
    }
    if (i < n) excl[i] = tmp[t] - v;
    if (t == SCAN_T - 1) bsum[blockIdx.x] = tmp[t];
}

__global__ void k_scan_sums(const int* __restrict__ bsum, int* __restrict__ boff, int nb) {
    __shared__ int tmp[128];
    int t = threadIdx.x;
    int v = (t < nb) ? bsum[t] : 0;
    tmp[t] = v;
    __syncthreads();
    for (int off = 1; off < 128; off <<= 1) {
        int u = (t >= off) ? tmp[t - off] : 0;
        __syncthreads();
        tmp[t] += u;
        __syncthreads();
    }
    if (t < nb) boff[t] = tmp[t] - v;
}

__global__ void k_scan_add1(const int* __restrict__ excl, const int* __restrict__ boff,
                            int* __restrict__ out, int n) {
    int i = blockIdx.x * blockDim.x + threadIdx.x;
    if (i < n) out[i] = excl[i] + boff[i / SCAN_T];
}

// ---------------- pass 2: scatter edges into bucket-partitioned array ----------------

__global__ __launch_bounds__(256) void k_binscatter(const int* __restrict__ src,
                                                    const int* __restrict__ dst,
                                                    const int* __restrict__ off,
                                                    int2* __restrict__ binned) {
    __shared__ int loff[NBUCK];
    int t = threadIdx.x;
    int blk = blockIdx.x;
    if (t < NBUCK) loff[t] = off[t * BBLK + blk];
    __syncthreads();
    int base = blk * CHUNK;
    for (int i = base + t; i < base + CHUNK; i += 256) {
        int d = dst[i];
        int s = src[i];
        int pos = atomicAdd(&loff[d >> 9], 1);
        binned[pos] = make_int2(s, d);
    }
}

// ---------------- pass 3: per-bucket degree/scan/fill entirely in LDS ----------------
// Produces row_start (with sentinel), dinv, csr_src. Zero global atomics.

__global__ __launch_bounds__(256) void k_bucket(const int2* __restrict__ binned,
                                                const int* __restrict__ off,
                                                int* __restrict__ row_start,
                                                float* __restrict__ dinv,
                                                int* __restrict__ csr_src) {
    __shared__ int cnt[512];
    __shared__ int ps[256];
    __shared__ int cur[512];
    int b = blockIdx.x;
    int t = threadIdx.x;
    int start = off[b * BBLK];
    int end = (b + 1 < NBUCK) ? off[(b + 1) * BBLK] : N_EDGES;
    cnt[t] = 0;
    cnt[t + 256] = 0;
    if (b == NBUCK - 1 && t == 0) row_start[N_NODES] = N_EDGES;  // sentinel
    __syncthreads();
    for (int i = start + t; i < end; i += 256) {
        atomicAdd(&cnt[binned[i].y & 511], 1);
    }
    __syncthreads();
    int a0 = cnt[2 * t], a1 = cnt[2 * t + 1];
    ps[t] = a0 + a1;
    __syncthreads();
    for (int o = 1; o < 256; o <<= 1) {
        int u = (t >= o) ? ps[t - o] : 0;
        __syncthreads();
        ps[t] += u;
        __syncthreads();
    }
    int pe = ps[t] - (a0 + a1);
    int e0 = start + pe;
    int e1 = e0 + a0;
    cur[2 * t] = e0;
    cur[2 * t + 1] = e1;
    int node0 = (b << 9) + 2 * t;
    if (node0 < N_NODES) {
        row_start[node0] = e0;
        dinv[node0] = rsqrtf((float)(a0 + 1));
    }
    if (node0 + 1 < N_NODES) {
        row_start[node0 + 1] = e1;
        dinv[node0 + 1] = rsqrtf((float)(a1 + 1));
    }
    __syncthreads();
    for (int i = start + t; i < end; i += 256) {
        int2 e = binned[i];
        int p = atomicAdd(&cur[e.y & 511], 1);
        csr_src[p] = e.x;
    }
}

// ---------------- cast + pre-scale: xs[i] = fp16(dinv[i] * x[i]) ----------------

__global__ __launch_bounds__(256) void k_cast_scale(const float* __restrict__ in,
                                                    const float* __restrict__ dinv,
                                                    __half* __restrict__ out) {
    int i = blockIdx.x * blockDim.x + threadIdx.x;  // over float4 groups, 32 per row
    if (i < N_NODES * 32) {
        float4 v = ((const float4*)in)[i];
        float d = dinv[i >> 5];
        ((__half2*)out)[2 * i]     = __floats2half2_rn(d * v.x, d * v.y);
        ((__half2*)out)[2 * i + 1] = __floats2half2_rn(d * v.z, d * v.w);
    }
}

// ---------------- weight prep: fp16 transposed (col-major) for MFMA B-fragments --------
// W1t[n][k] = W1[k][n]; Wct[n][k] = (n<64 ? Wmu[k][n] : Wls[k][n-64])

__global__ __launch_bounds__(256) void k_prepw(const float* __restrict__ W1,
                                               const float* __restrict__ Wmu,
                                               const float* __restrict__ Wls,
                                               __half* __restrict__ W1t,
                                               __half* __restrict__ Wct) {
    int i = blockIdx.x * blockDim.x + threadIdx.x;
    if (i < 128 * 128) {
        int n = i >> 7, k = i & 127;
        W1t[i] = __float2half(W1[k * 128 + n]);
        Wct[i] = __float2half(n < 64 ? Wmu[k * 64 + n] : Wls[k * 64 + (n - 64)]);
    }
}

// ---------------- aggregation: y[w] = dinv[w] * ( xs[w] + sum_{s in N(w)} xs[s] ) --------
// pre-scaled fp16 rows (256B), f32 accumulate. one wave per node; lane l = channels 2l,2l+1.

__global__ __launch_bounds__(256) void k_agg(const __half* __restrict__ in, __half* __restrict__ out,
                                             const int* __restrict__ csr_src,
                                             const int* __restrict__ row_start,
                                             const float* __restrict__ dinv) {
    int w = (blockIdx.x * 256 + threadIdx.x) >> 6;
    int lane = threadIdx.x & 63;
    int beg = row_start[w];
    int cnt = row_start[w + 1] - beg;
    float di = dinv[w];
    float2 acc = __half22float2(((const __half2*)(in + (size_t)w * 128))[lane]);  // self term
    int j = 0;
    for (; j + 7 < cnt; j += 8) {
        int s0 = csr_src[beg + j];
        int s1 = csr_src[beg + j + 1];
        int s2 = csr_src[beg + j + 2];
        int s3 = csr_src[beg + j + 3];
        int s4 = csr_src[beg + j + 4];
        int s5 = csr_src[beg + j + 5];
        int s6 = csr_src[beg + j + 6];
        int s7 = csr_src[beg + j + 7];
        float2 v0 = __half22float2(((const __half2*)(in + (size_t)s0 * 128))[lane]);
        float2 v1 = __half22float2(((const __half2*)(in + (size_t)s1 * 128))[lane]);
        float2 v2 = __half22float2(((const __half2*)(in + (size_t)s2 * 128))[lane]);
        float2 v3 = __half22float2(((const __half2*)(in + (size_t)s3 * 128))[lane]);
        float2 v4 = __half22float2(((const __half2*)(in + (size_t)s4 * 128))[lane]);
        float2 v5 = __half22float2(((const __half2*)(in + (size_t)s5 * 128))[lane]);
        float2 v6 = __half22float2(((const __half2*)(in + (size_t)s6 * 128))[lane]);
        float2 v7 = __half22float2(((const __half2*)(in + (size_t)s7 * 128))[lane]);
        acc.x += v0.x + v1.x + v2.x + v3.x + v4.x + v5.x + v6.x + v7.x;
        acc.y += v0.y + v1.y + v2.y + v3.y + v4.y + v5.y + v6.y + v7.y;
    }
    for (; j + 3 < cnt; j += 4) {
        int s0 = csr_src[beg + j];
        int s1 = csr_src[beg + j + 1];
        int s2 = csr_src[beg + j + 2];
        int s3 = csr_src[beg + j + 3];
        float2 v0 = __half22float2(((const __half2*)(in + (size_t)s0 * 128))[lane]);
        float2 v1 = __half22float2(((const __half2*)(in + (size_t)s1 * 128))[lane]);
        float2 v2 = __half22float2(((const __half2*)(in + (size_t)s2 * 128))[lane]);
        float2 v3 = __half22float2(((const __half2*)(in + (size_t)s3 * 128))[lane]);
        acc.x += v0.x + v1.x + v2.x + v3.x;
        acc.y += v0.y + v1.y + v2.y + v3.y;
    }
    for (; j < cnt; j++) {
        int s0 = csr_src[beg + j];
        float2 v0 = __half22float2(((const __half2*)(in + (size_t)s0 * 128))[lane]);
        acc.x += v0.x;
        acc.y += v0.y;
    }
    ((__half2*)(out + (size_t)w * 128))[lane] = __floats2half2_rn(di * acc.x, di * acc.y);
}

// ---------------- GEMM1 (MFMA): H = dinv * relu_normalize(relu(A @ W1 + b1)) ----------------
// block = 64 rows (4 waves x 16), N=128 (8 tiles), K=128 (4 steps of 32).
// A-frag: A[m=lane&15][k=quad*8+j]; B-frag: Wt[n=lane&15][k=quad*8+j]; D: col=lane&15,row=quad*4+reg.

__global__ __launch_bounds__(256) void k_gemm1(const __half* __restrict__ A,
                                               const __half* __restrict__ Wt,
                                               const float* __restrict__ b,
                                               const float* __restrict__ dinv,
                                               __half* __restrict__ H) {
    int t = threadIdx.x;
    int wv = t >> 6;
    int lane = t & 63;
    int m16 = lane & 15;
    int quad = lane >> 4;
    int row = blockIdx.x * 64 + wv * 16 + m16;
    floatx4 acc[8];
    #pragma unroll
    for (int tt = 0; tt < 8; tt++) acc[tt] = (floatx4){0.f, 0.f, 0.f, 0.f};
    #pragma unroll
    for (int kk = 0; kk < 4; kk++) {
        half8 a = *(const half8*)(A + (size_t)row * 128 + kk * 32 + quad * 8);
        #pragma unroll
        for (int tt = 0; tt < 8; tt++) {
            half8 bf = *(const half8*)(Wt + (size_t)(tt * 16 + m16) * 128 + kk * 32 + quad * 8);
            acc[tt] = __builtin_amdgcn_mfma_f32_16x16x32_f16(a, bf, acc[tt], 0, 0, 0);
        }
    }
    float bias[8];
    #pragma unroll
    for (int tt = 0; tt < 8; tt++) bias[tt] = b[tt * 16 + m16];
    int rbase = blockIdx.x * 64 + wv * 16 + quad * 4;
    #pragma unroll
    for (int r = 0; r < 4; r++) {
        int rw = rbase + r;
        float vv[8];
        float ssq = 0.f;
        #pragma unroll
        for (int tt = 0; tt < 8; tt++) {
            float v = fmaxf(acc[tt][r] + bias[tt], 0.f);
            vv[tt] = v;
            ssq += v * v;
        }
        ssq += __shfl_xor(ssq, 1, 64);
        ssq += __shfl_xor(ssq, 2, 64);
        ssq += __shfl_xor(ssq, 4, 64);
        ssq += __shfl_xor(ssq, 8, 64);
        float s = 1.0f / fmaxf(sqrtf(ssq), 1e-12f);
        if (rw < N_NODES) {
            float sc = s * dinv[rw];  // pre-scale for the next aggregation
            #pragma unroll
            for (int tt = 0; tt < 8; tt++) {
                H[(size_t)rw * 128 + tt * 16 + m16] = __float2half(vv[tt] * sc);
            }
        }
    }
}

// ---------------- GEMM2 (MFMA): out = [ Y2@Wmu+bmu | Y2@Wls+bls ] ----------------

__global__ __launch_bounds__(256) void k_gemm2(const __half* __restrict__ A,
                                               const __half* __restrict__ Wt,
                                               const float* __restrict__ bmu,
                                               const float* __restrict__ bls,
                                               float* __restrict__ out) {
    int t = threadIdx.x;
    int wv = t >> 6;
    int lane = t & 63;
    int m16 = lane & 15;
    int quad = lane >> 4;
    int row = blockIdx.x * 64 + wv * 16 + m16;
    floatx4 acc[8];
    #pragma unroll
    for (int tt = 0; tt < 8; tt++) acc[tt] = (floatx4){0.f, 0.f, 0.f, 0.f};
    #pragma unroll
    for (int kk = 0; kk < 4; kk++) {
        half8 a = *(const half8*)(A + (size_t)row * 128 + kk * 32 + quad * 8);
        #pragma unroll
        for (int tt = 0; tt < 8; tt++) {
            half8 bf = *(const half8*)(Wt + (size_t)(tt * 16 + m16) * 128 + kk * 32 + quad * 8);
            acc[tt] = __builtin_amdgcn_mfma_f32_16x16x32_f16(a, bf, acc[tt], 0, 0, 0);
        }
    }
    float bias[8];
    #pragma unroll
    for (int tt = 0; tt < 8; tt++)
        bias[tt] = (tt < 4) ? bmu[tt * 16 + m16] : bls[(tt - 4) * 16 + m16];
    int rbase = blockIdx.x * 64 + wv * 16 + quad * 4;
    #pragma unroll
    for (int r = 0; r < 4; r++) {
        int rw = rbase + r;
        if (rw < N_NODES) {
            #pragma unroll
            for (int tt = 0; tt < 4; tt++)
                out[(size_t)rw * 64 + tt * 16 + m16] = acc[tt][r] + bias[tt];
            #pragma unroll
            for (int tt = 4; tt < 8; tt++)
                out[(size_t)N_NODES * 64 + (size_t)rw * 64 + (tt - 4) * 16 + m16] = acc[tt][r] + bias[tt];
        }
    }
}

// ---------------- launch ----------------

extern "C" void kernel_launch(void* const* d_in, const int* in_sizes, int n_in,
                              void* d_out, int out_size, void* d_ws, size_t ws_size,
                              hipStream_t stream) {
    const float* x   = (const float*)d_in[0];
    const int*  eidx = (const int*)d_in[1];
    const float* W1  = (const float*)d_in[2];
    const float* b1  = (const float*)d_in[3];
    const float* Wmu = (const float*)d_in[4];
    const float* bmu = (const float*)d_in[5];
    const float* Wls = (const float*)d_in[6];
    const float* bls = (const float*)d_in[7];
    float* out = (float*)d_out;
    const int* e_src = eidx;
    const int* e_dst = eidx + N_EDGES;

    char* ws = (char*)d_ws;
    size_t off_b = 0;
    auto alloc = [&](size_t n) -> void* {
        void* p = ws + off_b;
        off_b += (n + 255) & ~(size_t)255;
        return p;
    };
    float*  dinv      = (float*)alloc((size_t)N_NODES * sizeof(float));
    int*    row_start = (int*)alloc((size_t)(N_NODES + 1) * sizeof(int));
    int*    hist      = (int*)alloc((size_t)NH * sizeof(int));
    int*    excl2     = (int*)alloc((size_t)NH * sizeof(int));
    int*    bsum2     = (int*)alloc(1024 * sizeof(int));
    int*    boff2     = (int*)alloc(1024 * sizeof(int));
    int*    offs      = (int*)alloc((size_t)NH * sizeof(int));
    int*    csr_src   = (int*)alloc((size_t)N_EDGES * sizeof(int));
    int2*   binned    = (int2*)alloc((size_t)N_EDGES * sizeof(int2));
    __half* W1t       = (__half*)alloc((size_t)128 * 128 * sizeof(__half));
    __half* Wct       = (__half*)alloc((size_t)128 * 128 * sizeof(__half));
    __half* xs        = (__half*)alloc((size_t)N_NODES * IN_CH * sizeof(__half));  // also reused as bufB (y2)
    __half* bufA      = (__half*)alloc((size_t)N_NODES * HID * sizeof(__half));    // y1
    __half* bufH      = (__half*)alloc((size_t)N_NODES * HID * sizeof(__half));    // hs = dinv*h
    alloc(32 * 1024);  // pad for OOB tile reads in last GEMM block
    __half* bufB = xs;  // xs is dead after agg1; reuse for y2

    const int NB_SCAN2 = (NH + SCAN_T - 1) / SCAN_T;  // 98
    const int NGEMM = (N_NODES + 63) / 64;            // 1563

    // weight prep (independent)
    hipLaunchKernelGGL(k_prepw, dim3(64), dim3(256), 0, stream, W1, Wmu, Wls, W1t, Wct);
    // CSR build: hist -> scan -> binscatter -> bucket (produces row_start, dinv, csr_src)
    hipLaunchKernelGGL(k_hist, dim3(BBLK), dim3(256), 0, stream, e_dst, hist);
    hipLaunchKernelGGL(k_scan_local, dim3(NB_SCAN2), dim3(SCAN_T), 0, stream, hist, excl2, bsum2, NH);
    hipLaunchKernelGGL(k_scan_sums, dim3(1), dim3(128), 0, stream, bsum2, boff2, NB_SCAN2);
    hipLaunchKernelGGL(k_scan_add1, dim3((NH + 255) / 256), dim3(256), 0, stream, excl2, boff2, offs, NH);
    hipLaunchKernelGGL(k_binscatter, dim3(BBLK), dim3(256), 0, stream, e_src, e_dst, offs, binned);
    hipLaunchKernelGGL(k_bucket, dim3(NBUCK), dim3(256), 0, stream, binned, offs, row_start, dinv, csr_src);
    // xs = fp16(dinv * x)  (needs dinv)
    hipLaunchKernelGGL(k_cast_scale, dim3((N_NODES * 32 + 255) / 256), dim3(256), 0, stream, x, dinv, xs);
    // layer 1
    hipLaunchKernelGGL(k_agg, dim3(N_NODES / 4), dim3(256), 0, stream, xs, bufA, csr_src, row_start, dinv);
    hipLaunchKernelGGL(k_gemm1, dim3(NGEMM), dim3(256), 0, stream, bufA, W1t, b1, dinv, bufH);
    // shared aggregation for layers 2+3
    hipLaunchKernelGGL(k_agg, dim3(N_NODES / 4), dim3(256), 0, stream, bufH, bufB, csr_src, row_start, dinv);
    hipLaunchKernelGGL(k_gemm2, dim3(NGEMM), dim3(256), 0, stream, bufB, Wct, bmu, bls, out);
}